// Round 5
// baseline (450.558 us; speedup 1.0000x reference)
//
#include <hip/hip_runtime.h>
#include <cstdint>

// ---------------------------------------------------------------------------
// Attention_75093208203309 on gfx950 — round 12.
// vs R11 (FAILED, absmax 0.498): fix the M1 orientation bug. R11 stored
// M1 = Wq^T@C row-major into Wqm, but the NT core needs B[1024+j][k] =
// M1[k][j] (M1^T rows) -> qc came out as x@M1^T. Fix: compute M1T = C^T@Wq
// directly by swapping prepared layouts (C3 = Ct A-side [hi|lo|hi], WqT3 =
// Wq^T B-side [hi|hi|lo]) and calling gemm_m1(A=C3, B=WqT3). parts then hold
// M1T row-major and the unchanged m1fin write IS the transpose-correct store.
// Everything else identical to R11:
//  * qc = x@(Wq^T C) + bq@C fused into G1 vs Wqm=[Wq;M1T] (N=2048).
//  * qs plain bf16 hi (S bitwise-identical to R10).
//  * G1 [L L L S] interleave; merged prep_all; compact-M chain via idx/cnt.
// Pipeline: prep_all -> m1 -> m1fin -> G1(k|q,qc|vt) -> S -> CL -> softmax
//           -> PV -> reduce.
// ---------------------------------------------------------------------------

typedef __attribute__((ext_vector_type(8))) short short8;
typedef __attribute__((ext_vector_type(4))) float f32x4;
typedef __attribute__((ext_vector_type(4))) float f4v;
typedef __attribute__((ext_vector_type(4))) unsigned short u16x4;
typedef __attribute__((ext_vector_type(8))) unsigned short u16x8;

typedef unsigned short u16;
typedef unsigned char u8;

__device__ __forceinline__ u16 f2bf(float f) {
  unsigned u = __float_as_uint(f);
  u += 0x7fffu + ((u >> 16) & 1u);   // RNE
  return (u16)(u >> 16);
}
__device__ __forceinline__ float bf2f(u16 h) {
  return __uint_as_float(((unsigned)h) << 16);
}

__device__ __forceinline__ void gld16(void* lds, const void* g) {
  __builtin_amdgcn_global_load_lds(
      (__attribute__((address_space(1))) void*)g,
      (__attribute__((address_space(3))) void*)lds,
      16, 0, 0);
}

// ---------------- merged prep kernel ----------------
// bid ranges:
//  [0,4096):    x -> xs3 [4096,3072] A-side [hi|lo|hi]
//  [4096,6144): Wk|Wv -> W3 [2048,3072] B-side [hi|hi|lo]
//  [6144,7168): Wq -> Wqm rows 0..1023 B-side [hi|hi|lo]
//  [7168,8192): Wq^T -> WqT3 [1024,3072] B-side [hi|hi|lo] (32x32 transpose)
//  [8192,9216): C -> C3 [1024,3072] = Ct A-side [hi|lo|hi]
//  [9216,9228): biases -> bp[3072]
//  9228:        bm -> idx[4096] (compact row list) + cnt
//  [9229,9233): b1[j] = sum_d bq[d]*C[d][j]  (f32 GEMV)
__global__ __launch_bounds__(256) void prep_all(
    const float* __restrict__ x, const float* __restrict__ Wq,
    const float* __restrict__ Wk, const float* __restrict__ Wv,
    const float* __restrict__ bq, const float* __restrict__ bk,
    const float* __restrict__ bv, const float* __restrict__ C,
    const float* __restrict__ bm,
    u16* __restrict__ xs3, u16* __restrict__ W3, u16* __restrict__ Wqm,
    u16* __restrict__ WqT3, u16* __restrict__ C3,
    float* __restrict__ bp, float* __restrict__ b1,
    int* __restrict__ idx, int* __restrict__ cntp) {
  __shared__ float tb[32][33];
  __shared__ int ps[256];
  const int bid = blockIdx.x, t = threadIdx.x;

  if (bid < 4096) {                       // x -> xs3
    int flat = (bid * 256 + t) * 4;
    int n = flat >> 10, i = flat & 1023;
    f4v v = *(const f4v*)(x + (size_t)flat);
    u16x4 hi, lo;
#pragma unroll
    for (int e = 0; e < 4; e++) {
      u16 h = f2bf(v[e]);
      hi[e] = h;
      lo[e] = f2bf(v[e] - bf2f(h));
    }
    size_t base = (size_t)n * 3072 + i;
    *(u16x4*)(xs3 + base) = hi;
    *(u16x4*)(xs3 + base + 1024) = lo;
    *(u16x4*)(xs3 + base + 2048) = hi;
  } else if (bid < 6144) {                // Wk|Wv -> W3 (B-side)
    int flat = ((bid - 4096) * 256 + t) * 4;
    int o = flat >> 10, i = flat & 1023;
    const float* src = (o < 1024) ? (Wk + (size_t)o * 1024)
                                  : (Wv + (size_t)(o - 1024) * 1024);
    f4v v = *(const f4v*)(src + i);
    u16x4 hi, lo;
#pragma unroll
    for (int e = 0; e < 4; e++) {
      u16 h = f2bf(v[e]);
      hi[e] = h;
      lo[e] = f2bf(v[e] - bf2f(h));
    }
    size_t base = (size_t)o * 3072 + i;
    *(u16x4*)(W3 + base) = hi;
    *(u16x4*)(W3 + base + 1024) = hi;
    *(u16x4*)(W3 + base + 2048) = lo;
  } else if (bid < 7168) {                // Wq -> Wqm rows 0..1023 (B-side)
    int flat = ((bid - 6144) * 256 + t) * 4;
    int o = flat >> 10, i = flat & 1023;
    f4v v = *(const f4v*)(Wq + (size_t)o * 1024 + i);
    u16x4 hi, lo;
#pragma unroll
    for (int e = 0; e < 4; e++) {
      u16 h = f2bf(v[e]);
      hi[e] = h;
      lo[e] = f2bf(v[e] - bf2f(h));
    }
    size_t base = (size_t)o * 3072 + i;
    *(u16x4*)(Wqm + base) = hi;
    *(u16x4*)(Wqm + base + 1024) = hi;
    *(u16x4*)(Wqm + base + 2048) = lo;
  } else if (bid < 8192) {                // Wq^T -> WqT3 (B-side [hi|hi|lo])
    int tt = bid - 7168;
    int lx = t & 31, ly = t >> 5;
    int i0 = (tt & 31) * 32, j0 = (tt >> 5) * 32;
#pragma unroll
    for (int r = 0; r < 32; r += 8)
      tb[ly + r][lx] = Wq[(size_t)(i0 + ly + r) * 1024 + j0 + lx];
    __syncthreads();
#pragma unroll
    for (int r = 0; r < 32; r += 8) {
      float f = tb[lx][ly + r];           // = Wq[i0+lx][j0+ly+r]
      u16 h = f2bf(f);
      u16 l = f2bf(f - bf2f(h));
      size_t o = (size_t)(j0 + ly + r) * 3072 + i0 + lx;
      WqT3[o] = h;
      WqT3[o + 1024] = h;
      WqT3[o + 2048] = l;
    }
  } else if (bid < 9216) {                // C -> C3 = Ct A-side [hi|lo|hi]
    int tt = bid - 8192;
    int lx = t & 31, ly = t >> 5;
    int i0 = (tt & 31) * 32, j0 = (tt >> 5) * 32;
#pragma unroll
    for (int r = 0; r < 32; r += 8)
      tb[ly + r][lx] = C[(size_t)(i0 + ly + r) * 1024 + j0 + lx];
    __syncthreads();
#pragma unroll
    for (int r = 0; r < 32; r += 8) {
      float f = tb[lx][ly + r];           // = C[i0+lx][j0+ly+r]
      u16 h = f2bf(f);
      u16 l = f2bf(f - bf2f(h));
      size_t o = (size_t)(j0 + ly + r) * 3072 + i0 + lx;
      C3[o] = h;
      C3[o + 1024] = l;
      C3[o + 2048] = h;
    }
  } else if (bid < 9228) {                // biases
    int id = (bid - 9216) * 256 + t;
    float v = (id < 1024) ? bq[id] : (id < 2048) ? bk[id - 1024] : bv[id - 2048];
    bp[id] = v;
  } else if (bid == 9228) {               // bm scan -> idx, cnt
    int c = 0;
    for (int e = 0; e < 16; e++) {
      int r = t * 16 + e;
      if (bm[r] != 0.0f) c++;
    }
    ps[t] = c;
    __syncthreads();
    for (int off = 1; off < 256; off <<= 1) {
      int v = (t >= off) ? ps[t - off] : 0;
      __syncthreads();
      ps[t] += v;
      __syncthreads();
    }
    int p = ps[t] - c;
    for (int e = 0; e < 16; e++) {
      int r = t * 16 + e;
      if (bm[r] != 0.0f) idx[p++] = r;
    }
    int cn = ps[255];
    if (t == 0) cntp[0] = cn;
    for (int r = cn + t; r < 4096; r += 256) idx[r] = 0;
  } else {                                // b1 = bq @ C  (4 blocks x 256)
    int j = (bid - 9229) * 256 + t;
    float a = 0.f;
    for (int d = 0; d < 1024; d++) a += bq[d] * C[(size_t)d * 1024 + j];
    b1[j] = a;
  }
}

// ---------------- NT GEMM core, 128x128, BK=64 + XOR bank swizzle ----------
// C[M,N] = A[M,K] @ B[N,K]^T, bf16 in, fp32 accum, 128x128 tile, 4 waves,
// 16x16x32 bf16 MFMA, global_load_lds width 16, 64-deep K-step.
// Optional ridx: A-side row gather. LDS swizzle: row r chunk c at slot
// c ^ (r&7); 0 bank conflicts (verified R7). ONE call site per kernel (R9
// lesson: each inlined call site gets its own 32KB LDS allocation).

struct EpiG1 {  // mode 0: k (B-side); 1: q(plain hi)|qc(A-side); 2: vt
  const float* bp; const float* b1;
  u16* qs; u16* k3; u16* qc3; u16* vt; int mode;
  __device__ void operator()(int r, int c, float v) const {
    if (mode == 0) {
      v += bp[1024 + c];
      u16 h = f2bf(v);
      u16 l = f2bf(v - bf2f(h));
      size_t b = (size_t)r * 3072 + c;
      k3[b] = h; k3[b + 1024] = h; k3[b + 2048] = l;
    } else if (mode == 1) {
      if (c < 1024) {
        qs[(size_t)r * 1024 + c] = f2bf(v + bp[c]);
      } else {
        float w = v + b1[c - 1024];
        u16 h = f2bf(w);
        u16 l = f2bf(w - bf2f(h));
        size_t b = (size_t)r * 3072 + (c - 1024);
        qc3[b] = h; qc3[b + 1024] = l; qc3[b + 2048] = h;   // A-side
      }
    } else {
      v += bp[2048 + r];
      vt[(size_t)r * 4096 + c] = f2bf(v);
    }
  }
};

struct EpiM1 {        // M1T split-K partial store (r = M1T row j, c = col i)
  float* part;
  __device__ void operator()(int r, int c, float v) const {
    part[(size_t)r * 1024 + c] = v;
  }
};

struct EpiS {         // S bf16 store (compact rows)
  u16* Sc;
  __device__ void operator()(int r, int c, float v) const {
    Sc[(size_t)r * 4096 + c] = f2bf(v);
  }
};

struct EpiCL {        // CL: straight-through mask bit (compact rows)
  u8* st; float b0;
  __device__ void operator()(int r, int c, float v) const {
    st[(size_t)r * 4096 + c] = (v + b0 > 0.f) ? 1 : 0;
  }
};

struct EpiPart {      // PV split-K: scatter partial to original row space
  float* part; const int* idx; int cnt;
  __device__ void operator()(int r, int c, float v) const {
    if (r < cnt) part[(size_t)idx[r] * 1024 + c] = v;
  }
};

template <class Epi>
__device__ __forceinline__ void gemm_core(
    const u16* __restrict__ A, const u16* __restrict__ B,
    int lda, int ldb, int K, int mBase, int nBase,
    const int* __restrict__ ridx, Epi epi) {
  __shared__ __align__(16) u16 lA[128 * 64];
  __shared__ __align__(16) u16 lB[128 * 64];
  const int tid = threadIdx.x;
  const int wave = tid >> 6, lane = tid & 63;
  const int wm = wave & 1, wn = wave >> 1;
  const int lane16 = lane & 15, quad = lane >> 4;

  const int srow = tid >> 3;
  const int gchunk = ((tid & 7) ^ (srow & 7)) * 8;
  const u16* aPi[4];
#pragma unroll
  for (int i = 0; i < 4; i++) {
    int row = mBase + srow + 32 * i;
    int g = ridx ? ridx[row] : row;
    aPi[i] = A + (size_t)g * lda + gchunk;
  }
  const u16* bP = B + (size_t)(nBase + srow) * ldb + gchunk;
  const int woff = wave * 1024;

  const int rsw = lane16 & 7;
  const u16* raB = lA + (wm * 64 + lane16) * 64;
  const u16* rbB = lB + (wn * 64 + lane16) * 64;

  f32x4 acc[4][4];
#pragma unroll
  for (int i = 0; i < 4; i++)
#pragma unroll
    for (int j = 0; j < 4; j++) acc[i][j] = (f32x4){0.f, 0.f, 0.f, 0.f};

  for (int k0 = 0; k0 < K; k0 += 64) {
#pragma unroll
    for (int i = 0; i < 4; i++) {
      gld16((char*)lA + i * 4096 + woff, aPi[i] + k0);
      gld16((char*)lB + i * 4096 + woff, bP + (size_t)(32 * i) * ldb + k0);
    }
    __syncthreads();
    short8 af[2][4], bfr[2][4];
#pragma unroll
    for (int s = 0; s < 2; s++) {
      const int sl = (((s << 2) + quad) ^ rsw) * 8;
#pragma unroll
      for (int j = 0; j < 4; j++) {
        af[s][j]  = *(const short8*)(raB + j * 1024 + sl);
        bfr[s][j] = *(const short8*)(rbB + j * 1024 + sl);
      }
    }
#pragma unroll
    for (int s = 0; s < 2; s++)
#pragma unroll
      for (int im = 0; im < 4; im++)
#pragma unroll
        for (int in = 0; in < 4; in++)
          acc[im][in] = __builtin_amdgcn_mfma_f32_16x16x32_bf16(
              af[s][im], bfr[s][in], acc[im][in], 0, 0, 0);
    __syncthreads();
  }

#pragma unroll
  for (int im = 0; im < 4; im++)
#pragma unroll
    for (int in = 0; in < 4; in++)
#pragma unroll
      for (int i = 0; i < 4; i++) {
        int r = mBase + wm * 64 + im * 16 + quad * 4 + i;
        int c = nBase + wn * 64 + in * 16 + lane16;
        epi(r, c, acc[im][in][i]);
      }
}

// M1T = C^T @ Wq, split-K=4 (K=768 each) -> f32 partials. 256 blocks.
// A = C3 (Ct A-side), B = WqT3 (Wq^T B-side):
//   out[j][i] = sum_d Ct[j][d]*WqT[i][d] = sum_d C[d][j]*Wq[d][i] = M1[i][j].
__global__ __launch_bounds__(256, 2) void gemm_m1(
    const u16* __restrict__ C3, const u16* __restrict__ WqT3,
    float* __restrict__ parts) {
  const int z = blockIdx.x >> 6, tile = blockIdx.x & 63;
  gemm_core(C3 + z * 768, WqT3 + z * 768, 3072, 3072, 768,
            (tile >> 3) * 128, (tile & 7) * 128, nullptr,
            EpiM1{parts + (size_t)z * 1024 * 1024});
}

// combine M1T partials -> B-side [hi|hi|lo] into Wqm rows 1024..2047.
// parts row j holds M1T[j][.] = M1[.][j] -> Wqm[1024+j][i] = M1[i][j], which
// is exactly the B-row the NT core needs for output column 1024+j.
__global__ void m1fin(const float* __restrict__ parts, u16* __restrict__ Wqm) {
  int flat = (blockIdx.x * 256 + threadIdx.x) * 4;
  int j = flat >> 10, i = flat & 1023;
  const size_t SL = (size_t)1024 * 1024;
  f4v p0 = *(const f4v*)(parts + (size_t)flat);
  f4v p1 = *(const f4v*)(parts + SL + flat);
  f4v p2 = *(const f4v*)(parts + 2 * SL + flat);
  f4v p3 = *(const f4v*)(parts + 3 * SL + flat);
  u16x4 hi, lo;
#pragma unroll
  for (int e = 0; e < 4; e++) {
    float f = (p0[e] + p1[e]) + (p2[e] + p3[e]);
    u16 h = f2bf(f);
    hi[e] = h;
    lo[e] = f2bf(f - bf2f(h));
  }
  size_t base = (size_t)(1024 + j) * 3072 + i;
  *(u16x4*)(Wqm + base) = hi;
  *(u16x4*)(Wqm + base + 1024) = hi;
  *(u16x4*)(Wqm + base + 2048) = lo;
}

// G1, 1-D grid 1024, [L L L S] interleave (sel = bid&3):
//  long L = (bid>>2)*3 + sel:
//    L<256:      k = xs3@Wk^T (K=3072, full M):    m=(L>>3)*128, n=(L&7)*128
//    L>=256:     q|qc = gather(xs3)@Wqm^T (K=3072, N=2048, compact M):
//                t=L-256: m=(t>>4)*128 (exit>=cnt), n=(t&15)*128
//  short (sel==3): vt = Wv_hi@x_hi^T (K=1024): s=bid>>2: m=(s&7)*128, n=(s>>3)*128
__global__ __launch_bounds__(256, 2) void gemm_g1(
    const u16* __restrict__ xs3, const u16* __restrict__ W3,
    const u16* __restrict__ Wqm, const float* __restrict__ bp,
    const float* __restrict__ b1, u16* __restrict__ qs,
    u16* __restrict__ k3, u16* __restrict__ qc3, u16* __restrict__ vt,
    const int* __restrict__ idx, const int* __restrict__ cntp) {
  const int bid = blockIdx.x;
  const int sel = bid & 3;
  const u16 *A, *B;
  const int* rx = nullptr;
  int K, mB, nB, mode;
  if (sel < 3) {
    const int L = (bid >> 2) * 3 + sel;
    if (L < 256) {
      A = xs3; B = W3; K = 3072;
      mB = (L >> 3) * 128; nB = (L & 7) * 128; mode = 0;
    } else {
      const int t = L - 256;
      mB = (t >> 4) * 128;
      if (mB >= cntp[0]) return;
      A = xs3; B = Wqm; K = 3072; nB = (t & 15) * 128; rx = idx; mode = 1;
    }
  } else {
    const int s = bid >> 2;
    A = W3 + (size_t)1024 * 3072; B = xs3; K = 1024;
    mB = (s & 7) * 128; nB = (s >> 3) * 128; mode = 2;
  }
  gemm_core(A, B, 3072, 3072, K, mB, nB, rx,
            EpiG1{bp, b1, qs, k3, qc3, vt, mode});
}

// S = q_hi @ k_hi^T (K=1024); compact M, grid 1024, early-exit. Balanced.
__global__ __launch_bounds__(256, 2) void gemm_s(
    const u16* __restrict__ qs, const u16* __restrict__ k3,
    u16* __restrict__ Sc, const int* __restrict__ cntp) {
  const int t = blockIdx.x;
  const int mB = (t >> 5) * 128;
  if (mB >= cntp[0]) return;
  gemm_core(qs, k3, 1024, 3072, 1024, mB, (t & 31) * 128, nullptr, EpiS{Sc});
}

// CL = qc3 @ k3^T (K=3072) -> st bits; compact M, grid 1024, early-exit.
__global__ __launch_bounds__(256, 2) void gemm_cl(
    const u16* __restrict__ qc3, const u16* __restrict__ k3,
    const float* __restrict__ bias, u8* __restrict__ st,
    const int* __restrict__ cntp) {
  const int bid = blockIdx.x;
  const int mBase = (bid >> 5) * 128;
  if (mBase >= cntp[0]) return;
  gemm_core(qc3, k3, 3072, 3072, 3072, mBase, (bid & 31) * 128, nullptr,
            EpiCL{st, bias[0]});
}

// PV split-K=4: grid 1024: z=bid>>8, rem=bid&255: m=(rem>>3)*128 (exit),
// n=(rem&7)*128. Partials scattered to original row space.
__global__ __launch_bounds__(256, 2) void gemm_pv(
    const u16* __restrict__ P, const u16* __restrict__ vt,
    float* __restrict__ p01, float* __restrict__ p23,
    const int* __restrict__ idx, const int* __restrict__ cntp) {
  const int bid = blockIdx.x;
  const int z = bid >> 8, rem = bid & 255;
  const int cnt = cntp[0];
  const int mBase = (rem >> 3) * 128;
  if (mBase >= cnt) return;
  float* base = ((z < 2) ? p01 : p23) + (size_t)(z & 1) * (4096ull * 1024ull);
  const size_t kOff = (size_t)z * 1024;
  gemm_core(P + kOff, vt + kOff, 4096, 4096, 1024, mBase, (rem & 7) * 128,
            nullptr, EpiPart{base, idx, cnt});
}

// out = (1-bm)*x + bm*(p0+p1+p2+p3); bm==0 rows skip partial loads.
__global__ void reduce_out(const float* __restrict__ x, const float* __restrict__ bm,
                           const float* __restrict__ p01, const float* __restrict__ p23,
                           float* __restrict__ out) {
  int id = blockIdx.x * 256 + threadIdx.x;
  int flat = id * 4;
  int r = flat >> 10;
  float b = bm[r];
  f4v xv = *(const f4v*)(x + (size_t)flat);
  f4v o;
  if (b != 0.0f) {
    const size_t SL = (size_t)4096 * 1024;
    f4v a0 = *(const f4v*)(p01 + (size_t)flat);
    f4v a1 = *(const f4v*)(p01 + SL + flat);
    f4v a2 = *(const f4v*)(p23 + (size_t)flat);
    f4v a3 = *(const f4v*)(p23 + SL + flat);
#pragma unroll
    for (int e = 0; e < 4; e++)
      o[e] = b * ((a0[e] + a1[e]) + (a2[e] + a3[e])) + (1.0f - b) * xv[e];
  } else {
    o = xv;
  }
  *(f4v*)(out + (size_t)flat) = o;
}

// ---------------- mask + softmax (compact rows, am/lm gathered) ------------
__global__ __launch_bounds__(256) void mask_softmax(
    const u16* __restrict__ Sc, const u8* __restrict__ st,
    const float* __restrict__ am, const float* __restrict__ lm,
    u16* __restrict__ P, const int* __restrict__ idx,
    const int* __restrict__ cntp) {
  const int n = blockIdx.x, tid = threadIdx.x;
  if (n >= cntp[0]) return;
  const int orow = idx[n];
  const int lane = tid & 63, wave = tid >> 6;
  const u16* Srow = Sc + (size_t)n * 4096;
  const u8* Trow = st + (size_t)n * 4096;
  const float* Arow = am + (size_t)orow * 4096;
  const float* Lrow = lm + (size_t)orow * 4096;

  float lg[16];
  float mx = -3.4e38f;
#pragma unroll
  for (int j = 0; j < 2; j++) {
    int base = (tid + 256 * j) * 8;
    u16x8 s8 = *(const u16x8*)(Srow + base);
    unsigned long long t8 = *(const unsigned long long*)(Trow + base);
    f4v a0 = *(const f4v*)(Arow + base), a1 = *(const f4v*)(Arow + base + 4);
    f4v l0 = *(const f4v*)(Lrow + base), l1 = *(const f4v*)(Lrow + base + 4);
#pragma unroll
    for (int e = 0; e < 8; e++) {
      float stv = ((t8 >> (8 * e)) & 1ull) ? 1.f : 0.f;
      float a = (e < 4) ? a0[e] : a1[e - 4];
      float l = (e < 4) ? l0[e] : l1[e - 4];
      float mv = a + stv * l;
      float v = bf2f(s8[e]) * 0.03125f - 10000.f * (1.f - mv);
      lg[j * 8 + e] = v;
      mx = fmaxf(mx, v);
    }
  }
#pragma unroll
  for (int o = 32; o; o >>= 1) mx = fmaxf(mx, __shfl_xor(mx, o));
  __shared__ float smax[4], ssum[4];
  if (lane == 0) smax[wave] = mx;
  __syncthreads();
  mx = fmaxf(fmaxf(smax[0], smax[1]), fmaxf(smax[2], smax[3]));

  float sum = 0.f;
#pragma unroll
  for (int i = 0; i < 16; i++) { lg[i] = __expf(lg[i] - mx); sum += lg[i]; }
#pragma unroll
  for (int o = 32; o; o >>= 1) sum += __shfl_xor(sum, o);
  if (lane == 0) ssum[wave] = sum;
  __syncthreads();
  float inv = 1.f / (ssum[0] + ssum[1] + ssum[2] + ssum[3]);

  u16* Pr = P + (size_t)n * 4096;
#pragma unroll
  for (int j = 0; j < 2; j++) {
    int base = (tid + 256 * j) * 8;
    u16x8 o8;
#pragma unroll
    for (int e = 0; e < 8; e++) o8[e] = f2bf(lg[j * 8 + e] * inv);
    *(u16x8*)(Pr + base) = o8;
  }
}

// ---------------- launch ----------------

extern "C" void kernel_launch(void* const* d_in, const int* in_sizes, int n_in,
                              void* d_out, int out_size, void* d_ws, size_t ws_size,
                              hipStream_t stream) {
  const float* x    = (const float*)d_in[0];
  const float* am   = (const float*)d_in[1];
  const float* lm   = (const float*)d_in[2];
  const float* bm   = (const float*)d_in[3];
  const float* Wq   = (const float*)d_in[4];
  const float* bq   = (const float*)d_in[5];
  const float* Wk   = (const float*)d_in[6];
  const float* bk   = (const float*)d_in[7];
  const float* Wv   = (const float*)d_in[8];
  const float* bv   = (const float*)d_in[9];
  const float* Cc   = (const float*)d_in[10];
  const float* bias = (const float*)d_in[11];
  float* out = (float*)d_out;
  char* ws = (char*)d_ws;

  if (ws_size < 0xB010000) return;  // ~176 MB scratch

  u16*  xs3  = (u16*) (ws + 0x0000000);  // 24 MB [x_hi|x_lo|x_hi]
  u16*  W3   = (u16*) (ws + 0x1800000);  // 12 MB [Wk | Wv] B-side
  u16*  Wqm  = (u16*) (ws + 0x2400000);  // 12 MB [Wq | M1T] B-side
  u16*  C3   = (u16*) (ws + 0x3000000);  //  6 MB Ct A-side
  u16*  WqT3 = (u16*) (ws + 0x3600000);  //  6 MB Wq^T B-side
  float* bp  = (float*)(ws + 0x3C00000); // 12 KB
  float* b1  = (float*)(ws + 0x3C04000); //  4 KB  bq@C
  int*  idx  = (int*)  (ws + 0x3C08000); // 16 KB compact->orig row map
  int*  cnt  = (int*)  (ws + 0x3C0C000); //  4 B
  u16*  qs   = (u16*) (ws + 0x3D00000);  //  8 MB q hi (plain, compact)
  u16*  qc3  = (u16*) (ws + 0x4500000);  // 24 MB [qc_hi|qc_lo|qc_hi] (compact)
  u16*  k3   = (u16*) (ws + 0x5D00000);  // 24 MB [k_hi|k_hi|k_lo] (full)
  u16*  vt   = (u16*) (ws + 0x7500000);  //  8 MB v^T [1024,4096]
  u16*  Sc   = (u16*) (ws + 0x7D00000);  // 32 MB bf16 S (compact)
  u8*   st   = (u8*)  (ws + 0x9D00000);  // 16 MB st bits (compact); end 0xAD00000
  // overlays:
  float* m1parts = (float*)(ws + 0x7D00000); // 16 MB (dead before Sc written)
  u16*  P    = (u16*) (ws + 0x0000000);  // 32 MB (xs3 + W3-head dead post-G1)
  float* parts01 = (float*)(ws + 0x4500000); // 32 MB (qc3 + k3-head, dead post-CL)
  float* parts23 = (float*)(ws + 0x7D00000); // 32 MB (Sc, dead post-softmax)

  // all preps in one kernel (x, W-layouts, Wq^T, Ct, biases, bm-scan, b1)
  prep_all<<<9233, 256, 0, stream>>>(x, Wq, Wk, Wv, bq, bk, bv, Cc, bm,
                                     xs3, W3, Wqm, WqT3, C3, bp, b1, idx, cnt);
  // M1T = C^T @ Wq (split-K=4) -> partials -> Wqm rows 1024..2047
  gemm_m1<<<256, 256, 0, stream>>>(C3, WqT3, m1parts);
  m1fin<<<1024, 256, 0, stream>>>(m1parts, Wqm);
  // G1: k | q,qc (fused vs [Wq;M1T], gathered rows) | vt, [L L L S] order
  gemm_g1<<<1024, 256, 0, stream>>>(xs3, W3, Wqm, bp, b1, qs, k3, qc3, vt,
                                    idx, cnt);
  // S = q_hi @ k_hi^T
  gemm_s<<<1024, 256, 0, stream>>>(qs, k3, Sc, cnt);
  // CL = qc3 @ k3^T -> st bits
  gemm_cl<<<1024, 256, 0, stream>>>(qc3, k3, bias, st, cnt);
  // mask + softmax -> P (bf16, compact rows)
  mask_softmax<<<4096, 256, 0, stream>>>(Sc, st, am, lm, P, idx, cnt);
  // PV: parts[z] = P @ vt^T over K-quarters, scattered to original rows
  gemm_pv<<<1024, 256, 0, stream>>>(P, vt, parts01, parts23, idx, cnt);
  // out = (1-bm)x + bm*(p0+p1+p2+p3)
  reduce_out<<<4096, 256, 0, stream>>>(x, bm, parts01, parts23, out);
}

// Round 6
// 427.252 us; speedup vs baseline: 1.0545x; 1.0545x over previous
//
#include <hip/hip_runtime.h>
#include <cstdint>

// ---------------------------------------------------------------------------
// Attention_75093208203309 on gfx950 — round 13.
// vs R12 (450us): packing fixes, no numeric change (absmax must stay
// 0.009765625).
//  * G1 becomes a job-loop kernel (grid 768, ONE gemm_core call site; LDS
//    stays 32KB): blocks 0..255 run {k-tile (48 K-steps), vt-tile (16)} = 64
//    units; blocks 256..767 run one q|qc tile (48); dead tail exits. First
//    wave = 512 resident = 256 (k+vt) + 256 q|qc -> makespan 64 units vs
//    R12's 96 (two stacked longs), packing 58% -> 87%.
//  * S and CL merge into gemm_scl (grid 2048, live-first m-major): 512 CL
//    blocks (48u) fill all slots, 512 S blocks (16u) backfill as CL drains ->
//    ~100% packing, one fewer launch gap.
//  * PV grid reordered m-major (live blocks contiguous).
// Pipeline: prep_all -> m1 -> m1fin -> G1{k+vt | q,qc} -> SCL -> softmax
//           -> PV -> reduce.
// ---------------------------------------------------------------------------

typedef __attribute__((ext_vector_type(8))) short short8;
typedef __attribute__((ext_vector_type(4))) float f32x4;
typedef __attribute__((ext_vector_type(4))) float f4v;
typedef __attribute__((ext_vector_type(4))) unsigned short u16x4;
typedef __attribute__((ext_vector_type(8))) unsigned short u16x8;

typedef unsigned short u16;
typedef unsigned char u8;

__device__ __forceinline__ u16 f2bf(float f) {
  unsigned u = __float_as_uint(f);
  u += 0x7fffu + ((u >> 16) & 1u);   // RNE
  return (u16)(u >> 16);
}
__device__ __forceinline__ float bf2f(u16 h) {
  return __uint_as_float(((unsigned)h) << 16);
}

__device__ __forceinline__ void gld16(void* lds, const void* g) {
  __builtin_amdgcn_global_load_lds(
      (__attribute__((address_space(1))) void*)g,
      (__attribute__((address_space(3))) void*)lds,
      16, 0, 0);
}

// ---------------- merged prep kernel ----------------
// bid ranges:
//  [0,4096):    x -> xs3 [4096,3072] A-side [hi|lo|hi]
//  [4096,6144): Wk|Wv -> W3 [2048,3072] B-side [hi|hi|lo]
//  [6144,7168): Wq -> Wqm rows 0..1023 B-side [hi|hi|lo]
//  [7168,8192): Wq^T -> WqT3 [1024,3072] B-side [hi|hi|lo] (32x32 transpose)
//  [8192,9216): C -> C3 [1024,3072] = Ct A-side [hi|lo|hi]
//  [9216,9228): biases -> bp[3072]
//  9228:        bm -> idx[4096] (compact row list) + cnt
//  [9229,9233): b1[j] = sum_d bq[d]*C[d][j]  (f32 GEMV)
__global__ __launch_bounds__(256) void prep_all(
    const float* __restrict__ x, const float* __restrict__ Wq,
    const float* __restrict__ Wk, const float* __restrict__ Wv,
    const float* __restrict__ bq, const float* __restrict__ bk,
    const float* __restrict__ bv, const float* __restrict__ C,
    const float* __restrict__ bm,
    u16* __restrict__ xs3, u16* __restrict__ W3, u16* __restrict__ Wqm,
    u16* __restrict__ WqT3, u16* __restrict__ C3,
    float* __restrict__ bp, float* __restrict__ b1,
    int* __restrict__ idx, int* __restrict__ cntp) {
  __shared__ float tb[32][33];
  __shared__ int ps[256];
  const int bid = blockIdx.x, t = threadIdx.x;

  if (bid < 4096) {                       // x -> xs3
    int flat = (bid * 256 + t) * 4;
    int n = flat >> 10, i = flat & 1023;
    f4v v = *(const f4v*)(x + (size_t)flat);
    u16x4 hi, lo;
#pragma unroll
    for (int e = 0; e < 4; e++) {
      u16 h = f2bf(v[e]);
      hi[e] = h;
      lo[e] = f2bf(v[e] - bf2f(h));
    }
    size_t base = (size_t)n * 3072 + i;
    *(u16x4*)(xs3 + base) = hi;
    *(u16x4*)(xs3 + base + 1024) = lo;
    *(u16x4*)(xs3 + base + 2048) = hi;
  } else if (bid < 6144) {                // Wk|Wv -> W3 (B-side)
    int flat = ((bid - 4096) * 256 + t) * 4;
    int o = flat >> 10, i = flat & 1023;
    const float* src = (o < 1024) ? (Wk + (size_t)o * 1024)
                                  : (Wv + (size_t)(o - 1024) * 1024);
    f4v v = *(const f4v*)(src + i);
    u16x4 hi, lo;
#pragma unroll
    for (int e = 0; e < 4; e++) {
      u16 h = f2bf(v[e]);
      hi[e] = h;
      lo[e] = f2bf(v[e] - bf2f(h));
    }
    size_t base = (size_t)o * 3072 + i;
    *(u16x4*)(W3 + base) = hi;
    *(u16x4*)(W3 + base + 1024) = hi;
    *(u16x4*)(W3 + base + 2048) = lo;
  } else if (bid < 7168) {                // Wq -> Wqm rows 0..1023 (B-side)
    int flat = ((bid - 6144) * 256 + t) * 4;
    int o = flat >> 10, i = flat & 1023;
    f4v v = *(const f4v*)(Wq + (size_t)o * 1024 + i);
    u16x4 hi, lo;
#pragma unroll
    for (int e = 0; e < 4; e++) {
      u16 h = f2bf(v[e]);
      hi[e] = h;
      lo[e] = f2bf(v[e] - bf2f(h));
    }
    size_t base = (size_t)o * 3072 + i;
    *(u16x4*)(Wqm + base) = hi;
    *(u16x4*)(Wqm + base + 1024) = hi;
    *(u16x4*)(Wqm + base + 2048) = lo;
  } else if (bid < 8192) {                // Wq^T -> WqT3 (B-side [hi|hi|lo])
    int tt = bid - 7168;
    int lx = t & 31, ly = t >> 5;
    int i0 = (tt & 31) * 32, j0 = (tt >> 5) * 32;
#pragma unroll
    for (int r = 0; r < 32; r += 8)
      tb[ly + r][lx] = Wq[(size_t)(i0 + ly + r) * 1024 + j0 + lx];
    __syncthreads();
#pragma unroll
    for (int r = 0; r < 32; r += 8) {
      float f = tb[lx][ly + r];           // = Wq[i0+lx][j0+ly+r]
      u16 h = f2bf(f);
      u16 l = f2bf(f - bf2f(h));
      size_t o = (size_t)(j0 + ly + r) * 3072 + i0 + lx;
      WqT3[o] = h;
      WqT3[o + 1024] = h;
      WqT3[o + 2048] = l;
    }
  } else if (bid < 9216) {                // C -> C3 = Ct A-side [hi|lo|hi]
    int tt = bid - 8192;
    int lx = t & 31, ly = t >> 5;
    int i0 = (tt & 31) * 32, j0 = (tt >> 5) * 32;
#pragma unroll
    for (int r = 0; r < 32; r += 8)
      tb[ly + r][lx] = C[(size_t)(i0 + ly + r) * 1024 + j0 + lx];
    __syncthreads();
#pragma unroll
    for (int r = 0; r < 32; r += 8) {
      float f = tb[lx][ly + r];           // = C[i0+lx][j0+ly+r]
      u16 h = f2bf(f);
      u16 l = f2bf(f - bf2f(h));
      size_t o = (size_t)(j0 + ly + r) * 3072 + i0 + lx;
      C3[o] = h;
      C3[o + 1024] = l;
      C3[o + 2048] = h;
    }
  } else if (bid < 9228) {                // biases
    int id = (bid - 9216) * 256 + t;
    float v = (id < 1024) ? bq[id] : (id < 2048) ? bk[id - 1024] : bv[id - 2048];
    bp[id] = v;
  } else if (bid == 9228) {               // bm scan -> idx, cnt
    int c = 0;
    for (int e = 0; e < 16; e++) {
      int r = t * 16 + e;
      if (bm[r] != 0.0f) c++;
    }
    ps[t] = c;
    __syncthreads();
    for (int off = 1; off < 256; off <<= 1) {
      int v = (t >= off) ? ps[t - off] : 0;
      __syncthreads();
      ps[t] += v;
      __syncthreads();
    }
    int p = ps[t] - c;
    for (int e = 0; e < 16; e++) {
      int r = t * 16 + e;
      if (bm[r] != 0.0f) idx[p++] = r;
    }
    int cn = ps[255];
    if (t == 0) cntp[0] = cn;
    for (int r = cn + t; r < 4096; r += 256) idx[r] = 0;
  } else {                                // b1 = bq @ C  (4 blocks x 256)
    int j = (bid - 9229) * 256 + t;
    float a = 0.f;
    for (int d = 0; d < 1024; d++) a += bq[d] * C[(size_t)d * 1024 + j];
    b1[j] = a;
  }
}

// ---------------- NT GEMM core, 128x128, BK=64 + XOR bank swizzle ----------
// C[M,N] = A[M,K] @ B[N,K]^T, bf16 in, fp32 accum, 128x128 tile, 4 waves,
// 16x16x32 bf16 MFMA, global_load_lds width 16, 64-deep K-step.
// Optional ridx: A-side row gather. LDS swizzle: row r chunk c at slot
// c ^ (r&7); 0 bank conflicts (verified R7). ONE call site per kernel (R9
// lesson: each inlined call site gets its own 32KB LDS allocation) — job
// loops reuse the single call site.

struct EpiG1 {  // mode 0: k (B-side); 1: q(plain hi)|qc(A-side); 2: vt
  const float* bp; const float* b1;
  u16* qs; u16* k3; u16* qc3; u16* vt; int mode;
  __device__ void operator()(int r, int c, float v) const {
    if (mode == 0) {
      v += bp[1024 + c];
      u16 h = f2bf(v);
      u16 l = f2bf(v - bf2f(h));
      size_t b = (size_t)r * 3072 + c;
      k3[b] = h; k3[b + 1024] = h; k3[b + 2048] = l;
    } else if (mode == 1) {
      if (c < 1024) {
        qs[(size_t)r * 1024 + c] = f2bf(v + bp[c]);
      } else {
        float w = v + b1[c - 1024];
        u16 h = f2bf(w);
        u16 l = f2bf(w - bf2f(h));
        size_t b = (size_t)r * 3072 + (c - 1024);
        qc3[b] = h; qc3[b + 1024] = l; qc3[b + 2048] = h;   // A-side
      }
    } else {
      v += bp[2048 + r];
      vt[(size_t)r * 4096 + c] = f2bf(v);
    }
  }
};

struct EpiM1 {        // M1T split-K partial store (r = M1T row j, c = col i)
  float* part;
  __device__ void operator()(int r, int c, float v) const {
    part[(size_t)r * 1024 + c] = v;
  }
};

struct EpiSCL {       // merged S | CL epilogue (compact rows)
  u16* Sc; u8* st; float b0; int isS;
  __device__ void operator()(int r, int c, float v) const {
    if (isS) Sc[(size_t)r * 4096 + c] = f2bf(v);
    else st[(size_t)r * 4096 + c] = (v + b0 > 0.f) ? 1 : 0;
  }
};

struct EpiPart {      // PV split-K: scatter partial to original row space
  float* part; const int* idx; int cnt;
  __device__ void operator()(int r, int c, float v) const {
    if (r < cnt) part[(size_t)idx[r] * 1024 + c] = v;
  }
};

template <class Epi>
__device__ __forceinline__ void gemm_core(
    const u16* __restrict__ A, const u16* __restrict__ B,
    int lda, int ldb, int K, int mBase, int nBase,
    const int* __restrict__ ridx, Epi epi) {
  __shared__ __align__(16) u16 lA[128 * 64];
  __shared__ __align__(16) u16 lB[128 * 64];
  const int tid = threadIdx.x;
  const int wave = tid >> 6, lane = tid & 63;
  const int wm = wave & 1, wn = wave >> 1;
  const int lane16 = lane & 15, quad = lane >> 4;

  const int srow = tid >> 3;
  const int gchunk = ((tid & 7) ^ (srow & 7)) * 8;
  const u16* aPi[4];
#pragma unroll
  for (int i = 0; i < 4; i++) {
    int row = mBase + srow + 32 * i;
    int g = ridx ? ridx[row] : row;
    aPi[i] = A + (size_t)g * lda + gchunk;
  }
  const u16* bP = B + (size_t)(nBase + srow) * ldb + gchunk;
  const int woff = wave * 1024;

  const int rsw = lane16 & 7;
  const u16* raB = lA + (wm * 64 + lane16) * 64;
  const u16* rbB = lB + (wn * 64 + lane16) * 64;

  f32x4 acc[4][4];
#pragma unroll
  for (int i = 0; i < 4; i++)
#pragma unroll
    for (int j = 0; j < 4; j++) acc[i][j] = (f32x4){0.f, 0.f, 0.f, 0.f};

  for (int k0 = 0; k0 < K; k0 += 64) {
#pragma unroll
    for (int i = 0; i < 4; i++) {
      gld16((char*)lA + i * 4096 + woff, aPi[i] + k0);
      gld16((char*)lB + i * 4096 + woff, bP + (size_t)(32 * i) * ldb + k0);
    }
    __syncthreads();
    short8 af[2][4], bfr[2][4];
#pragma unroll
    for (int s = 0; s < 2; s++) {
      const int sl = (((s << 2) + quad) ^ rsw) * 8;
#pragma unroll
      for (int j = 0; j < 4; j++) {
        af[s][j]  = *(const short8*)(raB + j * 1024 + sl);
        bfr[s][j] = *(const short8*)(rbB + j * 1024 + sl);
      }
    }
#pragma unroll
    for (int s = 0; s < 2; s++)
#pragma unroll
      for (int im = 0; im < 4; im++)
#pragma unroll
        for (int in = 0; in < 4; in++)
          acc[im][in] = __builtin_amdgcn_mfma_f32_16x16x32_bf16(
              af[s][im], bfr[s][in], acc[im][in], 0, 0, 0);
    __syncthreads();
  }

#pragma unroll
  for (int im = 0; im < 4; im++)
#pragma unroll
    for (int in = 0; in < 4; in++)
#pragma unroll
      for (int i = 0; i < 4; i++) {
        int r = mBase + wm * 64 + im * 16 + quad * 4 + i;
        int c = nBase + wn * 64 + in * 16 + lane16;
        epi(r, c, acc[im][in][i]);
      }
}

// M1T = C^T @ Wq, split-K=4 (K=768 each) -> f32 partials. 256 blocks.
__global__ __launch_bounds__(256, 2) void gemm_m1(
    const u16* __restrict__ C3, const u16* __restrict__ WqT3,
    float* __restrict__ parts) {
  const int z = blockIdx.x >> 6, tile = blockIdx.x & 63;
  gemm_core(C3 + z * 768, WqT3 + z * 768, 3072, 3072, 768,
            (tile >> 3) * 128, (tile & 7) * 128, nullptr,
            EpiM1{parts + (size_t)z * 1024 * 1024});
}

// combine M1T partials -> B-side [hi|hi|lo] into Wqm rows 1024..2047.
__global__ void m1fin(const float* __restrict__ parts, u16* __restrict__ Wqm) {
  int flat = (blockIdx.x * 256 + threadIdx.x) * 4;
  int j = flat >> 10, i = flat & 1023;
  const size_t SL = (size_t)1024 * 1024;
  f4v p0 = *(const f4v*)(parts + (size_t)flat);
  f4v p1 = *(const f4v*)(parts + SL + flat);
  f4v p2 = *(const f4v*)(parts + 2 * SL + flat);
  f4v p3 = *(const f4v*)(parts + 3 * SL + flat);
  u16x4 hi, lo;
#pragma unroll
  for (int e = 0; e < 4; e++) {
    float f = (p0[e] + p1[e]) + (p2[e] + p3[e]);
    u16 h = f2bf(f);
    hi[e] = h;
    lo[e] = f2bf(f - bf2f(h));
  }
  size_t base = (size_t)(1024 + j) * 3072 + i;
  *(u16x4*)(Wqm + base) = hi;
  *(u16x4*)(Wqm + base + 1024) = hi;
  *(u16x4*)(Wqm + base + 2048) = lo;
}

// G1 job-loop kernel, grid 768, ONE gemm_core call site (32KB LDS):
//  bid<256:  job0 = k-tile (K=3072, 48u): m=(bid>>3)*128, n=(bid&7)*128
//            job1 = vt-tile (K=1024, 16u): m=(bid&7)*128, n=(bid>>3)*128
//  bid>=256: job0 = q|qc tile (K=3072, N=2048, compact M, m-major):
//            t=bid-256: m=(t>>4)*128 (exit if >=cnt), n=(t&15)*128
// First wave = 256 (k+vt, 64u) + 256 (q|qc, 48u) -> makespan ~64u.
__global__ __launch_bounds__(256, 2) void gemm_g1(
    const u16* __restrict__ xs3, const u16* __restrict__ W3,
    const u16* __restrict__ Wqm, const float* __restrict__ bp,
    const float* __restrict__ b1, u16* __restrict__ qs,
    u16* __restrict__ k3, u16* __restrict__ qc3, u16* __restrict__ vt,
    const int* __restrict__ idx, const int* __restrict__ cntp) {
  const int bid = blockIdx.x;
  const int cnt = cntp[0];
  for (int j = 0; j < 2; ++j) {
    const u16 *A, *B;
    const int* rx = nullptr;
    int K, mB, nB, mode;
    if (j == 0) {
      if (bid < 256) {                     // k tile
        A = xs3; B = W3; K = 3072;
        mB = (bid >> 3) * 128; nB = (bid & 7) * 128; mode = 0;
      } else {                             // q|qc tile
        const int t = bid - 256;
        mB = (t >> 4) * 128;
        if (mB >= cnt) continue;
        A = xs3; B = Wqm; K = 3072; nB = (t & 15) * 128; rx = idx; mode = 1;
      }
    } else {
      if (bid >= 256) break;               // only k blocks carry vt
      A = W3 + (size_t)1024 * 3072; B = xs3; K = 1024;
      mB = (bid & 7) * 128; nB = (bid >> 3) * 128; mode = 2;
    }
    gemm_core(A, B, 3072, 3072, K, mB, nB, rx,
              EpiG1{bp, b1, qs, k3, qc3, vt, mode});
  }
}

// merged S | CL kernel, grid 2048, live-first m-major, ONE call site:
//  bid<1024:  CL tile: m=(bid>>5)*128 (exit if >=cnt), n=(bid&31)*128, K=3072
//  bid>=1024: S tile:  t=bid-1024: m=(t>>5)*128 (exit), n=(t&31)*128, K=1024
// 512 live CL (48u) fill all slots; 512 live S (16u) backfill as CL drains.
__global__ __launch_bounds__(256, 2) void gemm_scl(
    const u16* __restrict__ qs, const u16* __restrict__ qc3,
    const u16* __restrict__ k3, const float* __restrict__ bias,
    u16* __restrict__ Sc, u8* __restrict__ st,
    const int* __restrict__ cntp) {
  const int bid = blockIdx.x;
  const int cnt = cntp[0];
  const u16* A;
  int lda, K, mB, nB, isS;
  if (bid < 1024) {
    mB = (bid >> 5) * 128;
    if (mB >= cnt) return;
    A = qc3; lda = 3072; K = 3072; nB = (bid & 31) * 128; isS = 0;
  } else {
    const int t = bid - 1024;
    mB = (t >> 5) * 128;
    if (mB >= cnt) return;
    A = qs; lda = 1024; K = 1024; nB = (t & 31) * 128; isS = 1;
  }
  gemm_core(A, k3, lda, 3072, K, mB, nB, nullptr,
            EpiSCL{Sc, st, bias[0], isS});
}

// PV split-K=4, grid 1024, m-major (live blocks contiguous):
//  m=bid>>5 (exit if m*128>=cnt), rem=bid&31: z=rem>>3, n=rem&7.
__global__ __launch_bounds__(256, 2) void gemm_pv(
    const u16* __restrict__ P, const u16* __restrict__ vt,
    float* __restrict__ p01, float* __restrict__ p23,
    const int* __restrict__ idx, const int* __restrict__ cntp) {
  const int bid = blockIdx.x;
  const int m = bid >> 5, rem = bid & 31;
  const int z = rem >> 3, n = rem & 7;
  const int cnt = cntp[0];
  const int mBase = m * 128;
  if (mBase >= cnt) return;
  float* base = ((z < 2) ? p01 : p23) + (size_t)(z & 1) * (4096ull * 1024ull);
  const size_t kOff = (size_t)z * 1024;
  gemm_core(P + kOff, vt + kOff, 4096, 4096, 1024, mBase, n * 128,
            nullptr, EpiPart{base, idx, cnt});
}

// out = (1-bm)*x + bm*(p0+p1+p2+p3); bm==0 rows skip partial loads.
__global__ void reduce_out(const float* __restrict__ x, const float* __restrict__ bm,
                           const float* __restrict__ p01, const float* __restrict__ p23,
                           float* __restrict__ out) {
  int id = blockIdx.x * 256 + threadIdx.x;
  int flat = id * 4;
  int r = flat >> 10;
  float b = bm[r];
  f4v xv = *(const f4v*)(x + (size_t)flat);
  f4v o;
  if (b != 0.0f) {
    const size_t SL = (size_t)4096 * 1024;
    f4v a0 = *(const f4v*)(p01 + (size_t)flat);
    f4v a1 = *(const f4v*)(p01 + SL + flat);
    f4v a2 = *(const f4v*)(p23 + (size_t)flat);
    f4v a3 = *(const f4v*)(p23 + SL + flat);
#pragma unroll
    for (int e = 0; e < 4; e++)
      o[e] = b * ((a0[e] + a1[e]) + (a2[e] + a3[e])) + (1.0f - b) * xv[e];
  } else {
    o = xv;
  }
  *(f4v*)(out + (size_t)flat) = o;
}

// ---------------- mask + softmax (compact rows, am/lm gathered) ------------
__global__ __launch_bounds__(256) void mask_softmax(
    const u16* __restrict__ Sc, const u8* __restrict__ st,
    const float* __restrict__ am, const float* __restrict__ lm,
    u16* __restrict__ P, const int* __restrict__ idx,
    const int* __restrict__ cntp) {
  const int n = blockIdx.x, tid = threadIdx.x;
  if (n >= cntp[0]) return;
  const int orow = idx[n];
  const int lane = tid & 63, wave = tid >> 6;
  const u16* Srow = Sc + (size_t)n * 4096;
  const u8* Trow = st + (size_t)n * 4096;
  const float* Arow = am + (size_t)orow * 4096;
  const float* Lrow = lm + (size_t)orow * 4096;

  float lg[16];
  float mx = -3.4e38f;
#pragma unroll
  for (int j = 0; j < 2; j++) {
    int base = (tid + 256 * j) * 8;
    u16x8 s8 = *(const u16x8*)(Srow + base);
    unsigned long long t8 = *(const unsigned long long*)(Trow + base);
    f4v a0 = *(const f4v*)(Arow + base), a1 = *(const f4v*)(Arow + base + 4);
    f4v l0 = *(const f4v*)(Lrow + base), l1 = *(const f4v*)(Lrow + base + 4);
#pragma unroll
    for (int e = 0; e < 8; e++) {
      float stv = ((t8 >> (8 * e)) & 1ull) ? 1.f : 0.f;
      float a = (e < 4) ? a0[e] : a1[e - 4];
      float l = (e < 4) ? l0[e] : l1[e - 4];
      float mv = a + stv * l;
      float v = bf2f(s8[e]) * 0.03125f - 10000.f * (1.f - mv);
      lg[j * 8 + e] = v;
      mx = fmaxf(mx, v);
    }
  }
#pragma unroll
  for (int o = 32; o; o >>= 1) mx = fmaxf(mx, __shfl_xor(mx, o));
  __shared__ float smax[4], ssum[4];
  if (lane == 0) smax[wave] = mx;
  __syncthreads();
  mx = fmaxf(fmaxf(smax[0], smax[1]), fmaxf(smax[2], smax[3]));

  float sum = 0.f;
#pragma unroll
  for (int i = 0; i < 16; i++) { lg[i] = __expf(lg[i] - mx); sum += lg[i]; }
#pragma unroll
  for (int o = 32; o; o >>= 1) sum += __shfl_xor(sum, o);
  if (lane == 0) ssum[wave] = sum;
  __syncthreads();
  float inv = 1.f / (ssum[0] + ssum[1] + ssum[2] + ssum[3]);

  u16* Pr = P + (size_t)n * 4096;
#pragma unroll
  for (int j = 0; j < 2; j++) {
    int base = (tid + 256 * j) * 8;
    u16x8 o8;
#pragma unroll
    for (int e = 0; e < 8; e++) o8[e] = f2bf(lg[j * 8 + e] * inv);
    *(u16x8*)(Pr + base) = o8;
  }
}

// ---------------- launch ----------------

extern "C" void kernel_launch(void* const* d_in, const int* in_sizes, int n_in,
                              void* d_out, int out_size, void* d_ws, size_t ws_size,
                              hipStream_t stream) {
  const float* x    = (const float*)d_in[0];
  const float* am   = (const float*)d_in[1];
  const float* lm   = (const float*)d_in[2];
  const float* bm   = (const float*)d_in[3];
  const float* Wq   = (const float*)d_in[4];
  const float* bq   = (const float*)d_in[5];
  const float* Wk   = (const float*)d_in[6];
  const float* bk   = (const float*)d_in[7];
  const float* Wv   = (const float*)d_in[8];
  const float* bv   = (const float*)d_in[9];
  const float* Cc   = (const float*)d_in[10];
  const float* bias = (const float*)d_in[11];
  float* out = (float*)d_out;
  char* ws = (char*)d_ws;

  if (ws_size < 0xB010000) return;  // ~176 MB scratch

  u16*  xs3  = (u16*) (ws + 0x0000000);  // 24 MB [x_hi|x_lo|x_hi]
  u16*  W3   = (u16*) (ws + 0x1800000);  // 12 MB [Wk | Wv] B-side
  u16*  Wqm  = (u16*) (ws + 0x2400000);  // 12 MB [Wq | M1T] B-side
  u16*  C3   = (u16*) (ws + 0x3000000);  //  6 MB Ct A-side
  u16*  WqT3 = (u16*) (ws + 0x3600000);  //  6 MB Wq^T B-side
  float* bp  = (float*)(ws + 0x3C00000); // 12 KB
  float* b1  = (float*)(ws + 0x3C04000); //  4 KB  bq@C
  int*  idx  = (int*)  (ws + 0x3C08000); // 16 KB compact->orig row map
  int*  cnt  = (int*)  (ws + 0x3C0C000); //  4 B
  u16*  qs   = (u16*) (ws + 0x3D00000);  //  8 MB q hi (plain, compact)
  u16*  qc3  = (u16*) (ws + 0x4500000);  // 24 MB [qc_hi|qc_lo|qc_hi] (compact)
  u16*  k3   = (u16*) (ws + 0x5D00000);  // 24 MB [k_hi|k_hi|k_lo] (full)
  u16*  vt   = (u16*) (ws + 0x7500000);  //  8 MB v^T [1024,4096]
  u16*  Sc   = (u16*) (ws + 0x7D00000);  // 32 MB bf16 S (compact)
  u8*   st   = (u8*)  (ws + 0x9D00000);  // 16 MB st bits (compact); end 0xAD00000
  // overlays:
  float* m1parts = (float*)(ws + 0x7D00000); // 16 MB (dead before Sc written)
  u16*  P    = (u16*) (ws + 0x0000000);  // 32 MB (xs3 + W3-head dead post-G1)
  float* parts01 = (float*)(ws + 0x4500000); // 32 MB (qc3 + k3-head, dead post-CL)
  float* parts23 = (float*)(ws + 0x7D00000); // 32 MB (Sc, dead post-softmax)

  // all preps in one kernel (x, W-layouts, Wq^T, Ct, biases, bm-scan, b1)
  prep_all<<<9233, 256, 0, stream>>>(x, Wq, Wk, Wv, bq, bk, bv, Cc, bm,
                                     xs3, W3, Wqm, WqT3, C3, bp, b1, idx, cnt);
  // M1T = C^T @ Wq (split-K=4) -> partials -> Wqm rows 1024..2047
  gemm_m1<<<256, 256, 0, stream>>>(C3, WqT3, m1parts);
  m1fin<<<1024, 256, 0, stream>>>(m1parts, Wqm);
  // G1 job-loop: {k+vt} | {q,qc}  (fused vs [Wq;M1T], gathered rows)
  gemm_g1<<<768, 256, 0, stream>>>(xs3, W3, Wqm, bp, b1, qs, k3, qc3, vt,
                                   idx, cnt);
  // merged S | CL (CL blocks first; S backfills)
  gemm_scl<<<2048, 256, 0, stream>>>(qs, qc3, k3, bias, Sc, st, cnt);
  // mask + softmax -> P (bf16, compact rows)
  mask_softmax<<<4096, 256, 0, stream>>>(Sc, st, am, lm, P, idx, cnt);
  // PV: parts[z] = P @ vt^T over K-quarters, scattered to original rows
  gemm_pv<<<1024, 256, 0, stream>>>(P, vt, parts01, parts23, idx, cnt);
  // out = (1-bm)x + bm*(p0+p1+p2+p3)
  reduce_out<<<4096, 256, 0, stream>>>(x, bm, parts01, parts23, out);
}

// Round 7
// 420.938 us; speedup vs baseline: 1.0704x; 1.0150x over previous
//
#include <hip/hip_runtime.h>
#include <cstdint>

// ---------------------------------------------------------------------------
// Attention_75093208203309 on gfx950 — round 14.
// vs R13 (427us): occupancy + granularity fix, no numeric change.
// Diagnosis: long(48-step)-job count (256 k + nq*16 q|qc, nq=ceil(cnt/128),
// likely 17 -> 528) exceeded the 512 block slots at 2 blocks/CU -> 16
// stragglers ran 48..96u on an emptying machine. 96u ~= the measured 99-104us
// in BOTH R12 and R13. Fix:
//  * __launch_bounds__(256, 3) on all GEMM kernels -> 768 slots (LDS 96KB/CU,
//    VGPR cap 170 >> 72). m114: ~3 blocks/CU also captures barrier-drain
//    overlap -> MfmaUtil should rise.
//  * G1 job map re-shaped: 0-255 k | 256-543 q|qc (18 m-tiles) | 544-767
//    {q-overflow tiles 18-31 (normally dead, any-cnt correctness), then 1-2
//    vt}. All longs start at t=0 -> makespan 48u.
//  * SCL/PV/M1 unchanged grids (live-first m-major self-balances at 768).
// Pipeline: prep_all -> m1 -> m1fin -> G1 -> SCL -> softmax -> PV -> reduce.
// ---------------------------------------------------------------------------

typedef __attribute__((ext_vector_type(8))) short short8;
typedef __attribute__((ext_vector_type(4))) float f32x4;
typedef __attribute__((ext_vector_type(4))) float f4v;
typedef __attribute__((ext_vector_type(4))) unsigned short u16x4;
typedef __attribute__((ext_vector_type(8))) unsigned short u16x8;

typedef unsigned short u16;
typedef unsigned char u8;

__device__ __forceinline__ u16 f2bf(float f) {
  unsigned u = __float_as_uint(f);
  u += 0x7fffu + ((u >> 16) & 1u);   // RNE
  return (u16)(u >> 16);
}
__device__ __forceinline__ float bf2f(u16 h) {
  return __uint_as_float(((unsigned)h) << 16);
}

__device__ __forceinline__ void gld16(void* lds, const void* g) {
  __builtin_amdgcn_global_load_lds(
      (__attribute__((address_space(1))) void*)g,
      (__attribute__((address_space(3))) void*)lds,
      16, 0, 0);
}

// ---------------- merged prep kernel ----------------
// bid ranges:
//  [0,4096):    x -> xs3 [4096,3072] A-side [hi|lo|hi]
//  [4096,6144): Wk|Wv -> W3 [2048,3072] B-side [hi|hi|lo]
//  [6144,7168): Wq -> Wqm rows 0..1023 B-side [hi|hi|lo]
//  [7168,8192): Wq^T -> WqT3 [1024,3072] B-side [hi|hi|lo] (32x32 transpose)
//  [8192,9216): C -> C3 [1024,3072] = Ct A-side [hi|lo|hi]
//  [9216,9228): biases -> bp[3072]
//  9228:        bm -> idx[4096] (compact row list) + cnt
//  [9229,9233): b1[j] = sum_d bq[d]*C[d][j]  (f32 GEMV)
__global__ __launch_bounds__(256) void prep_all(
    const float* __restrict__ x, const float* __restrict__ Wq,
    const float* __restrict__ Wk, const float* __restrict__ Wv,
    const float* __restrict__ bq, const float* __restrict__ bk,
    const float* __restrict__ bv, const float* __restrict__ C,
    const float* __restrict__ bm,
    u16* __restrict__ xs3, u16* __restrict__ W3, u16* __restrict__ Wqm,
    u16* __restrict__ WqT3, u16* __restrict__ C3,
    float* __restrict__ bp, float* __restrict__ b1,
    int* __restrict__ idx, int* __restrict__ cntp) {
  __shared__ float tb[32][33];
  __shared__ int ps[256];
  const int bid = blockIdx.x, t = threadIdx.x;

  if (bid < 4096) {                       // x -> xs3
    int flat = (bid * 256 + t) * 4;
    int n = flat >> 10, i = flat & 1023;
    f4v v = *(const f4v*)(x + (size_t)flat);
    u16x4 hi, lo;
#pragma unroll
    for (int e = 0; e < 4; e++) {
      u16 h = f2bf(v[e]);
      hi[e] = h;
      lo[e] = f2bf(v[e] - bf2f(h));
    }
    size_t base = (size_t)n * 3072 + i;
    *(u16x4*)(xs3 + base) = hi;
    *(u16x4*)(xs3 + base + 1024) = lo;
    *(u16x4*)(xs3 + base + 2048) = hi;
  } else if (bid < 6144) {                // Wk|Wv -> W3 (B-side)
    int flat = ((bid - 4096) * 256 + t) * 4;
    int o = flat >> 10, i = flat & 1023;
    const float* src = (o < 1024) ? (Wk + (size_t)o * 1024)
                                  : (Wv + (size_t)(o - 1024) * 1024);
    f4v v = *(const f4v*)(src + i);
    u16x4 hi, lo;
#pragma unroll
    for (int e = 0; e < 4; e++) {
      u16 h = f2bf(v[e]);
      hi[e] = h;
      lo[e] = f2bf(v[e] - bf2f(h));
    }
    size_t base = (size_t)o * 3072 + i;
    *(u16x4*)(W3 + base) = hi;
    *(u16x4*)(W3 + base + 1024) = hi;
    *(u16x4*)(W3 + base + 2048) = lo;
  } else if (bid < 7168) {                // Wq -> Wqm rows 0..1023 (B-side)
    int flat = ((bid - 6144) * 256 + t) * 4;
    int o = flat >> 10, i = flat & 1023;
    f4v v = *(const f4v*)(Wq + (size_t)o * 1024 + i);
    u16x4 hi, lo;
#pragma unroll
    for (int e = 0; e < 4; e++) {
      u16 h = f2bf(v[e]);
      hi[e] = h;
      lo[e] = f2bf(v[e] - bf2f(h));
    }
    size_t base = (size_t)o * 3072 + i;
    *(u16x4*)(Wqm + base) = hi;
    *(u16x4*)(Wqm + base + 1024) = hi;
    *(u16x4*)(Wqm + base + 2048) = lo;
  } else if (bid < 8192) {                // Wq^T -> WqT3 (B-side [hi|hi|lo])
    int tt = bid - 7168;
    int lx = t & 31, ly = t >> 5;
    int i0 = (tt & 31) * 32, j0 = (tt >> 5) * 32;
#pragma unroll
    for (int r = 0; r < 32; r += 8)
      tb[ly + r][lx] = Wq[(size_t)(i0 + ly + r) * 1024 + j0 + lx];
    __syncthreads();
#pragma unroll
    for (int r = 0; r < 32; r += 8) {
      float f = tb[lx][ly + r];           // = Wq[i0+lx][j0+ly+r]
      u16 h = f2bf(f);
      u16 l = f2bf(f - bf2f(h));
      size_t o = (size_t)(j0 + ly + r) * 3072 + i0 + lx;
      WqT3[o] = h;
      WqT3[o + 1024] = h;
      WqT3[o + 2048] = l;
    }
  } else if (bid < 9216) {                // C -> C3 = Ct A-side [hi|lo|hi]
    int tt = bid - 8192;
    int lx = t & 31, ly = t >> 5;
    int i0 = (tt & 31) * 32, j0 = (tt >> 5) * 32;
#pragma unroll
    for (int r = 0; r < 32; r += 8)
      tb[ly + r][lx] = C[(size_t)(i0 + ly + r) * 1024 + j0 + lx];
    __syncthreads();
#pragma unroll
    for (int r = 0; r < 32; r += 8) {
      float f = tb[lx][ly + r];           // = C[i0+lx][j0+ly+r]
      u16 h = f2bf(f);
      u16 l = f2bf(f - bf2f(h));
      size_t o = (size_t)(j0 + ly + r) * 3072 + i0 + lx;
      C3[o] = h;
      C3[o + 1024] = l;
      C3[o + 2048] = h;
    }
  } else if (bid < 9228) {                // biases
    int id = (bid - 9216) * 256 + t;
    float v = (id < 1024) ? bq[id] : (id < 2048) ? bk[id - 1024] : bv[id - 2048];
    bp[id] = v;
  } else if (bid == 9228) {               // bm scan -> idx, cnt
    int c = 0;
    for (int e = 0; e < 16; e++) {
      int r = t * 16 + e;
      if (bm[r] != 0.0f) c++;
    }
    ps[t] = c;
    __syncthreads();
    for (int off = 1; off < 256; off <<= 1) {
      int v = (t >= off) ? ps[t - off] : 0;
      __syncthreads();
      ps[t] += v;
      __syncthreads();
    }
    int p = ps[t] - c;
    for (int e = 0; e < 16; e++) {
      int r = t * 16 + e;
      if (bm[r] != 0.0f) idx[p++] = r;
    }
    int cn = ps[255];
    if (t == 0) cntp[0] = cn;
    for (int r = cn + t; r < 4096; r += 256) idx[r] = 0;
  } else {                                // b1 = bq @ C  (4 blocks x 256)
    int j = (bid - 9229) * 256 + t;
    float a = 0.f;
    for (int d = 0; d < 1024; d++) a += bq[d] * C[(size_t)d * 1024 + j];
    b1[j] = a;
  }
}

// ---------------- NT GEMM core, 128x128, BK=64 + XOR bank swizzle ----------
// C[M,N] = A[M,K] @ B[N,K]^T, bf16 in, fp32 accum, 128x128 tile, 4 waves,
// 16x16x32 bf16 MFMA, global_load_lds width 16, 64-deep K-step.
// Optional ridx: A-side row gather. LDS swizzle: row r chunk c at slot
// c ^ (r&7); 0 bank conflicts (verified R7). ONE call site per kernel (R9
// lesson: each inlined call site gets its own 32KB LDS allocation) — job
// loops reuse the single call site. All GEMMs run 3 blocks/CU (R14).

struct EpiG1 {  // mode 0: k (B-side); 1: q(plain hi)|qc(A-side); 2: vt
  const float* bp; const float* b1;
  u16* qs; u16* k3; u16* qc3; u16* vt; int mode;
  __device__ void operator()(int r, int c, float v) const {
    if (mode == 0) {
      v += bp[1024 + c];
      u16 h = f2bf(v);
      u16 l = f2bf(v - bf2f(h));
      size_t b = (size_t)r * 3072 + c;
      k3[b] = h; k3[b + 1024] = h; k3[b + 2048] = l;
    } else if (mode == 1) {
      if (c < 1024) {
        qs[(size_t)r * 1024 + c] = f2bf(v + bp[c]);
      } else {
        float w = v + b1[c - 1024];
        u16 h = f2bf(w);
        u16 l = f2bf(w - bf2f(h));
        size_t b = (size_t)r * 3072 + (c - 1024);
        qc3[b] = h; qc3[b + 1024] = l; qc3[b + 2048] = h;   // A-side
      }
    } else {
      v += bp[2048 + r];
      vt[(size_t)r * 4096 + c] = f2bf(v);
    }
  }
};

struct EpiM1 {        // M1T split-K partial store (r = M1T row j, c = col i)
  float* part;
  __device__ void operator()(int r, int c, float v) const {
    part[(size_t)r * 1024 + c] = v;
  }
};

struct EpiSCL {       // merged S | CL epilogue (compact rows)
  u16* Sc; u8* st; float b0; int isS;
  __device__ void operator()(int r, int c, float v) const {
    if (isS) Sc[(size_t)r * 4096 + c] = f2bf(v);
    else st[(size_t)r * 4096 + c] = (v + b0 > 0.f) ? 1 : 0;
  }
};

struct EpiPart {      // PV split-K: scatter partial to original row space
  float* part; const int* idx; int cnt;
  __device__ void operator()(int r, int c, float v) const {
    if (r < cnt) part[(size_t)idx[r] * 1024 + c] = v;
  }
};

template <class Epi>
__device__ __forceinline__ void gemm_core(
    const u16* __restrict__ A, const u16* __restrict__ B,
    int lda, int ldb, int K, int mBase, int nBase,
    const int* __restrict__ ridx, Epi epi) {
  __shared__ __align__(16) u16 lA[128 * 64];
  __shared__ __align__(16) u16 lB[128 * 64];
  const int tid = threadIdx.x;
  const int wave = tid >> 6, lane = tid & 63;
  const int wm = wave & 1, wn = wave >> 1;
  const int lane16 = lane & 15, quad = lane >> 4;

  const int srow = tid >> 3;
  const int gchunk = ((tid & 7) ^ (srow & 7)) * 8;
  const u16* aPi[4];
#pragma unroll
  for (int i = 0; i < 4; i++) {
    int row = mBase + srow + 32 * i;
    int g = ridx ? ridx[row] : row;
    aPi[i] = A + (size_t)g * lda + gchunk;
  }
  const u16* bP = B + (size_t)(nBase + srow) * ldb + gchunk;
  const int woff = wave * 1024;

  const int rsw = lane16 & 7;
  const u16* raB = lA + (wm * 64 + lane16) * 64;
  const u16* rbB = lB + (wn * 64 + lane16) * 64;

  f32x4 acc[4][4];
#pragma unroll
  for (int i = 0; i < 4; i++)
#pragma unroll
    for (int j = 0; j < 4; j++) acc[i][j] = (f32x4){0.f, 0.f, 0.f, 0.f};

  for (int k0 = 0; k0 < K; k0 += 64) {
#pragma unroll
    for (int i = 0; i < 4; i++) {
      gld16((char*)lA + i * 4096 + woff, aPi[i] + k0);
      gld16((char*)lB + i * 4096 + woff, bP + (size_t)(32 * i) * ldb + k0);
    }
    __syncthreads();
    short8 af[2][4], bfr[2][4];
#pragma unroll
    for (int s = 0; s < 2; s++) {
      const int sl = (((s << 2) + quad) ^ rsw) * 8;
#pragma unroll
      for (int j = 0; j < 4; j++) {
        af[s][j]  = *(const short8*)(raB + j * 1024 + sl);
        bfr[s][j] = *(const short8*)(rbB + j * 1024 + sl);
      }
    }
#pragma unroll
    for (int s = 0; s < 2; s++)
#pragma unroll
      for (int im = 0; im < 4; im++)
#pragma unroll
        for (int in = 0; in < 4; in++)
          acc[im][in] = __builtin_amdgcn_mfma_f32_16x16x32_bf16(
              af[s][im], bfr[s][in], acc[im][in], 0, 0, 0);
    __syncthreads();
  }

#pragma unroll
  for (int im = 0; im < 4; im++)
#pragma unroll
    for (int in = 0; in < 4; in++)
#pragma unroll
      for (int i = 0; i < 4; i++) {
        int r = mBase + wm * 64 + im * 16 + quad * 4 + i;
        int c = nBase + wn * 64 + in * 16 + lane16;
        epi(r, c, acc[im][in][i]);
      }
}

// M1T = C^T @ Wq, split-K=4 (K=768 each) -> f32 partials. 256 blocks.
__global__ __launch_bounds__(256, 3) void gemm_m1(
    const u16* __restrict__ C3, const u16* __restrict__ WqT3,
    float* __restrict__ parts) {
  const int z = blockIdx.x >> 6, tile = blockIdx.x & 63;
  gemm_core(C3 + z * 768, WqT3 + z * 768, 3072, 3072, 768,
            (tile >> 3) * 128, (tile & 7) * 128, nullptr,
            EpiM1{parts + (size_t)z * 1024 * 1024});
}

// combine M1T partials -> B-side [hi|hi|lo] into Wqm rows 1024..2047.
__global__ void m1fin(const float* __restrict__ parts, u16* __restrict__ Wqm) {
  int flat = (blockIdx.x * 256 + threadIdx.x) * 4;
  int j = flat >> 10, i = flat & 1023;
  const size_t SL = (size_t)1024 * 1024;
  f4v p0 = *(const f4v*)(parts + (size_t)flat);
  f4v p1 = *(const f4v*)(parts + SL + flat);
  f4v p2 = *(const f4v*)(parts + 2 * SL + flat);
  f4v p3 = *(const f4v*)(parts + 3 * SL + flat);
  u16x4 hi, lo;
#pragma unroll
  for (int e = 0; e < 4; e++) {
    float f = (p0[e] + p1[e]) + (p2[e] + p3[e]);
    u16 h = f2bf(f);
    hi[e] = h;
    lo[e] = f2bf(f - bf2f(h));
  }
  size_t base = (size_t)(1024 + j) * 3072 + i;
  *(u16x4*)(Wqm + base) = hi;
  *(u16x4*)(Wqm + base + 1024) = hi;
  *(u16x4*)(Wqm + base + 2048) = lo;
}

// G1 job-loop kernel, grid 768 = 3/CU exactly, ONE gemm_core call site:
//  bid<256:        k-tile (K=3072, 48u): m=(bid>>3)*128, n=(bid&7)*128
//  bid in [256,544): q|qc tile (K=3072, N=2048): t=bid-256, m=(t>>4)*128
//                  (covers m-tiles 0..17, cnt<=2304; exit if m>=cnt)
//  bid>=544 (224 blocks):
//    pass0: q|qc overflow tile 18+(t>>4) (t=bid-544; normally dead, makes
//           any-cnt correct), pass1/2: vt tiles t and t+224 (K=1024, 16u).
// All long jobs start at t=0 -> makespan ~48u (vs 96u at 2/CU with 528 longs).
__global__ __launch_bounds__(256, 3) void gemm_g1(
    const u16* __restrict__ xs3, const u16* __restrict__ W3,
    const u16* __restrict__ Wqm, const float* __restrict__ bp,
    const float* __restrict__ b1, u16* __restrict__ qs,
    u16* __restrict__ k3, u16* __restrict__ qc3, u16* __restrict__ vt,
    const int* __restrict__ idx, const int* __restrict__ cntp) {
  const int bid = blockIdx.x;
  const int cnt = cntp[0];
  for (int pass = 0; pass < 3; ++pass) {
    const u16 *A, *B;
    const int* rx = nullptr;
    int K, mB, nB, mode;
    if (bid < 256) {
      if (pass) break;
      A = xs3; B = W3; K = 3072;
      mB = (bid >> 3) * 128; nB = (bid & 7) * 128; mode = 0;
    } else if (bid < 544) {
      if (pass) break;
      const int t = bid - 256;
      mB = (t >> 4) * 128;
      if (mB >= cnt) break;
      A = xs3; B = Wqm; K = 3072; nB = (t & 15) * 128; rx = idx; mode = 1;
    } else {
      const int t = bid - 544;
      if (pass == 0) {                     // overflow q|qc (m-tiles 18..31)
        mB = (18 + (t >> 4)) * 128;
        if (mB >= cnt) continue;           // normally dead -> fall to vt
        A = xs3; B = Wqm; K = 3072; nB = (t & 15) * 128; rx = idx; mode = 1;
      } else {                             // vt jobs t and t+224
        const int s = t + (pass - 1) * 224;
        if (s >= 256) break;
        A = W3 + (size_t)1024 * 3072; B = xs3; K = 1024;
        mB = (s & 7) * 128; nB = (s >> 3) * 128; mode = 2;
      }
    }
    gemm_core(A, B, 3072, 3072, K, mB, nB, rx,
              EpiG1{bp, b1, qs, k3, qc3, vt, mode});
  }
}

// merged S | CL kernel, grid 2048, live-first m-major, ONE call site:
//  bid<1024:  CL tile: m=(bid>>5)*128 (exit if >=cnt), n=(bid&31)*128, K=3072
//  bid>=1024: S tile:  t=bid-1024: m=(t>>5)*128 (exit), n=(t&31)*128, K=1024
// ~544 live CL (48u) + S (16u) over 768 slots -> makespan ~52u.
__global__ __launch_bounds__(256, 3) void gemm_scl(
    const u16* __restrict__ qs, const u16* __restrict__ qc3,
    const u16* __restrict__ k3, const float* __restrict__ bias,
    u16* __restrict__ Sc, u8* __restrict__ st,
    const int* __restrict__ cntp) {
  const int bid = blockIdx.x;
  const int cnt = cntp[0];
  const u16* A;
  int lda, K, mB, nB, isS;
  if (bid < 1024) {
    mB = (bid >> 5) * 128;
    if (mB >= cnt) return;
    A = qc3; lda = 3072; K = 3072; nB = (bid & 31) * 128; isS = 0;
  } else {
    const int t = bid - 1024;
    mB = (t >> 5) * 128;
    if (mB >= cnt) return;
    A = qs; lda = 1024; K = 1024; nB = (t & 31) * 128; isS = 1;
  }
  gemm_core(A, k3, lda, 3072, K, mB, nB, nullptr,
            EpiSCL{Sc, st, bias[0], isS});
}

// PV split-K=4, grid 1024, m-major (live blocks contiguous):
//  m=bid>>5 (exit if m*128>=cnt), rem=bid&31: z=rem>>3, n=rem&7.
__global__ __launch_bounds__(256, 3) void gemm_pv(
    const u16* __restrict__ P, const u16* __restrict__ vt,
    float* __restrict__ p01, float* __restrict__ p23,
    const int* __restrict__ idx, const int* __restrict__ cntp) {
  const int bid = blockIdx.x;
  const int m = bid >> 5, rem = bid & 31;
  const int z = rem >> 3, n = rem & 7;
  const int cnt = cntp[0];
  const int mBase = m * 128;
  if (mBase >= cnt) return;
  float* base = ((z < 2) ? p01 : p23) + (size_t)(z & 1) * (4096ull * 1024ull);
  const size_t kOff = (size_t)z * 1024;
  gemm_core(P + kOff, vt + kOff, 4096, 4096, 1024, mBase, n * 128,
            nullptr, EpiPart{base, idx, cnt});
}

// out = (1-bm)*x + bm*(p0+p1+p2+p3); bm==0 rows skip partial loads.
__global__ void reduce_out(const float* __restrict__ x, const float* __restrict__ bm,
                           const float* __restrict__ p01, const float* __restrict__ p23,
                           float* __restrict__ out) {
  int id = blockIdx.x * 256 + threadIdx.x;
  int flat = id * 4;
  int r = flat >> 10;
  float b = bm[r];
  f4v xv = *(const f4v*)(x + (size_t)flat);
  f4v o;
  if (b != 0.0f) {
    const size_t SL = (size_t)4096 * 1024;
    f4v a0 = *(const f4v*)(p01 + (size_t)flat);
    f4v a1 = *(const f4v*)(p01 + SL + flat);
    f4v a2 = *(const f4v*)(p23 + (size_t)flat);
    f4v a3 = *(const f4v*)(p23 + SL + flat);
#pragma unroll
    for (int e = 0; e < 4; e++)
      o[e] = b * ((a0[e] + a1[e]) + (a2[e] + a3[e])) + (1.0f - b) * xv[e];
  } else {
    o = xv;
  }
  *(f4v*)(out + (size_t)flat) = o;
}

// ---------------- mask + softmax (compact rows, am/lm gathered) ------------
__global__ __launch_bounds__(256) void mask_softmax(
    const u16* __restrict__ Sc, const u8* __restrict__ st,
    const float* __restrict__ am, const float* __restrict__ lm,
    u16* __restrict__ P, const int* __restrict__ idx,
    const int* __restrict__ cntp) {
  const int n = blockIdx.x, tid = threadIdx.x;
  if (n >= cntp[0]) return;
  const int orow = idx[n];
  const int lane = tid & 63, wave = tid >> 6;
  const u16* Srow = Sc + (size_t)n * 4096;
  const u8* Trow = st + (size_t)n * 4096;
  const float* Arow = am + (size_t)orow * 4096;
  const float* Lrow = lm + (size_t)orow * 4096;

  float lg[16];
  float mx = -3.4e38f;
#pragma unroll
  for (int j = 0; j < 2; j++) {
    int base = (tid + 256 * j) * 8;
    u16x8 s8 = *(const u16x8*)(Srow + base);
    unsigned long long t8 = *(const unsigned long long*)(Trow + base);
    f4v a0 = *(const f4v*)(Arow + base), a1 = *(const f4v*)(Arow + base + 4);
    f4v l0 = *(const f4v*)(Lrow + base), l1 = *(const f4v*)(Lrow + base + 4);
#pragma unroll
    for (int e = 0; e < 8; e++) {
      float stv = ((t8 >> (8 * e)) & 1ull) ? 1.f : 0.f;
      float a = (e < 4) ? a0[e] : a1[e - 4];
      float l = (e < 4) ? l0[e] : l1[e - 4];
      float mv = a + stv * l;
      float v = bf2f(s8[e]) * 0.03125f - 10000.f * (1.f - mv);
      lg[j * 8 + e] = v;
      mx = fmaxf(mx, v);
    }
  }
#pragma unroll
  for (int o = 32; o; o >>= 1) mx = fmaxf(mx, __shfl_xor(mx, o));
  __shared__ float smax[4], ssum[4];
  if (lane == 0) smax[wave] = mx;
  __syncthreads();
  mx = fmaxf(fmaxf(smax[0], smax[1]), fmaxf(smax[2], smax[3]));

  float sum = 0.f;
#pragma unroll
  for (int i = 0; i < 16; i++) { lg[i] = __expf(lg[i] - mx); sum += lg[i]; }
#pragma unroll
  for (int o = 32; o; o >>= 1) sum += __shfl_xor(sum, o);
  if (lane == 0) ssum[wave] = sum;
  __syncthreads();
  float inv = 1.f / (ssum[0] + ssum[1] + ssum[2] + ssum[3]);

  u16* Pr = P + (size_t)n * 4096;
#pragma unroll
  for (int j = 0; j < 2; j++) {
    int base = (tid + 256 * j) * 8;
    u16x8 o8;
#pragma unroll
    for (int e = 0; e < 8; e++) o8[e] = f2bf(lg[j * 8 + e] * inv);
    *(u16x8*)(Pr + base) = o8;
  }
}

// ---------------- launch ----------------

extern "C" void kernel_launch(void* const* d_in, const int* in_sizes, int n_in,
                              void* d_out, int out_size, void* d_ws, size_t ws_size,
                              hipStream_t stream) {
  const float* x    = (const float*)d_in[0];
  const float* am   = (const float*)d_in[1];
  const float* lm   = (const float*)d_in[2];
  const float* bm   = (const float*)d_in[3];
  const float* Wq   = (const float*)d_in[4];
  const float* bq   = (const float*)d_in[5];
  const float* Wk   = (const float*)d_in[6];
  const float* bk   = (const float*)d_in[7];
  const float* Wv   = (const float*)d_in[8];
  const float* bv   = (const float*)d_in[9];
  const float* Cc   = (const float*)d_in[10];
  const float* bias = (const float*)d_in[11];
  float* out = (float*)d_out;
  char* ws = (char*)d_ws;

  if (ws_size < 0xB010000) return;  // ~176 MB scratch

  u16*  xs3  = (u16*) (ws + 0x0000000);  // 24 MB [x_hi|x_lo|x_hi]
  u16*  W3   = (u16*) (ws + 0x1800000);  // 12 MB [Wk | Wv] B-side
  u16*  Wqm  = (u16*) (ws + 0x2400000);  // 12 MB [Wq | M1T] B-side
  u16*  C3   = (u16*) (ws + 0x3000000);  //  6 MB Ct A-side
  u16*  WqT3 = (u16*) (ws + 0x3600000);  //  6 MB Wq^T B-side
  float* bp  = (float*)(ws + 0x3C00000); // 12 KB
  float* b1  = (float*)(ws + 0x3C04000); //  4 KB  bq@C
  int*  idx  = (int*)  (ws + 0x3C08000); // 16 KB compact->orig row map
  int*  cnt  = (int*)  (ws + 0x3C0C000); //  4 B
  u16*  qs   = (u16*) (ws + 0x3D00000);  //  8 MB q hi (plain, compact)
  u16*  qc3  = (u16*) (ws + 0x4500000);  // 24 MB [qc_hi|qc_lo|qc_hi] (compact)
  u16*  k3   = (u16*) (ws + 0x5D00000);  // 24 MB [k_hi|k_hi|k_lo] (full)
  u16*  vt   = (u16*) (ws + 0x7500000);  //  8 MB v^T [1024,4096]
  u16*  Sc   = (u16*) (ws + 0x7D00000);  // 32 MB bf16 S (compact)
  u8*   st   = (u8*)  (ws + 0x9D00000);  // 16 MB st bits (compact); end 0xAD00000
  // overlays:
  float* m1parts = (float*)(ws + 0x7D00000); // 16 MB (dead before Sc written)
  u16*  P    = (u16*) (ws + 0x0000000);  // 32 MB (xs3 + W3-head dead post-G1)
  float* parts01 = (float*)(ws + 0x4500000); // 32 MB (qc3 + k3-head, dead post-CL)
  float* parts23 = (float*)(ws + 0x7D00000); // 32 MB (Sc, dead post-softmax)

  // all preps in one kernel (x, W-layouts, Wq^T, Ct, biases, bm-scan, b1)
  prep_all<<<9233, 256, 0, stream>>>(x, Wq, Wk, Wv, bq, bk, bv, Cc, bm,
                                     xs3, W3, Wqm, WqT3, C3, bp, b1, idx, cnt);
  // M1T = C^T @ Wq (split-K=4) -> partials -> Wqm rows 1024..2047
  gemm_m1<<<256, 256, 0, stream>>>(C3, WqT3, m1parts);
  m1fin<<<1024, 256, 0, stream>>>(m1parts, Wqm);
  // G1 job-loop: k | q,qc (18+14 m-tiles) | vt   (768 = 3/CU exactly)
  gemm_g1<<<768, 256, 0, stream>>>(xs3, W3, Wqm, bp, b1, qs, k3, qc3, vt,
                                   idx, cnt);
  // merged S | CL (CL blocks first; S backfills)
  gemm_scl<<<2048, 256, 0, stream>>>(qs, qc3, k3, bias, Sc, st, cnt);
  // mask + softmax -> P (bf16, compact rows)
  mask_softmax<<<4096, 256, 0, stream>>>(Sc, st, am, lm, P, idx, cnt);
  // PV: parts[z] = P @ vt^T over K-quarters, scattered to original rows
  gemm_pv<<<1024, 256, 0, stream>>>(P, vt, parts01, parts23, idx, cnt);
  // out = (1-bm)x + bm*(p0+p1+p2+p3)
  reduce_out<<<4096, 256, 0, stream>>>(x, bm, parts01, parts23, out);
}

// Round 9
// 418.565 us; speedup vs baseline: 1.0764x; 1.0057x over previous
//
#include <hip/hip_runtime.h>
#include <cstdint>

// ---------------------------------------------------------------------------
// Attention_75093208203309 on gfx950 — round 16.
// vs R15 (FAILED 0.1056): revert to R14's PROVEN numerics (triple-bf16 CL
// chain, absmax 0.009765625) — R15 showed every 2-term compromise lands too
// close to the 0.0994 threshold (M1-input error alone contributes dCL~0.13).
// vs R14 (421us): kill the hi-duplication in the triple layouts. Triple
// buffers stored [hi|lo|hi]/[hi|hi|lo] at 6B/elem purely so the K-loop reads
// a contiguous 3072-wide panel. K-steps (64) never straddle 1024-chunk
// boundaries, so a per-step chunk remap in staging (k0a = k0>=2048?k0-2048:k0
// for A-side, k0b = k0>=1024?k0-1024:k0 for B-side) reads the SAME values
// from 2-term [hi|lo] physical storage (4B/elem). Bitwise-identical MFMA
// sequence; -33% triple-GEMM epilogue writes (G1 WRITE 53.6->~37MB), -33%
// buffer footprint (better L2), -27% prep writes.
// Pipeline: prep_all -> m1 -> m1fin -> G1 -> SCL -> softmax -> PV -> reduce.
// ---------------------------------------------------------------------------

typedef __attribute__((ext_vector_type(8))) short short8;
typedef __attribute__((ext_vector_type(4))) float f32x4;
typedef __attribute__((ext_vector_type(4))) float f4v;
typedef __attribute__((ext_vector_type(4))) unsigned short u16x4;
typedef __attribute__((ext_vector_type(8))) unsigned short u16x8;

typedef unsigned short u16;
typedef unsigned char u8;

__device__ __forceinline__ u16 f2bf(float f) {
  unsigned u = __float_as_uint(f);
  u += 0x7fffu + ((u >> 16) & 1u);   // RNE
  return (u16)(u >> 16);
}
__device__ __forceinline__ float bf2f(u16 h) {
  return __uint_as_float(((unsigned)h) << 16);
}

__device__ __forceinline__ void gld16(void* lds, const void* g) {
  __builtin_amdgcn_global_load_lds(
      (__attribute__((address_space(1))) void*)g,
      (__attribute__((address_space(3))) void*)lds,
      16, 0, 0);
}

// ---------------- merged prep kernel ----------------
// All 2-term buffers are [rows][2048]: hi at col 0..1023, lo at 1024..2047.
// bid ranges (grid 9233):
//  [0,4096):    x -> x2 [4096][2048]
//  [4096,5120): Wq -> Wqm2 rows 0..1023
//  [5120,6144): Wk -> Wk2
//  [6144,7168): Wv -> Wv2
//  [7168,8192): C -> Ct2 (32x32 transpose: Ct2[j] holds C[.][j])
//  [8192,9216): Wq -> WqT2 (transpose)
//  [9216,9228): biases -> bp[3072]
//  9228:        bm -> idx[4096] + cnt
//  [9229,9233): b1[j] = sum_d bq[d]*C[d][j]  (f32 GEMV)
__global__ __launch_bounds__(256) void prep_all(
    const float* __restrict__ x, const float* __restrict__ Wq,
    const float* __restrict__ Wk, const float* __restrict__ Wv,
    const float* __restrict__ bq, const float* __restrict__ bk,
    const float* __restrict__ bv, const float* __restrict__ C,
    const float* __restrict__ bm,
    u16* __restrict__ x2, u16* __restrict__ Wqm2, u16* __restrict__ Wk2,
    u16* __restrict__ Wv2, u16* __restrict__ Ct2, u16* __restrict__ WqT2,
    float* __restrict__ bp, float* __restrict__ b1,
    int* __restrict__ idx, int* __restrict__ cntp) {
  __shared__ float tb[32][33];
  __shared__ int ps[256];
  const int bid = blockIdx.x, t = threadIdx.x;

  if (bid < 7168) {                       // f32 -> [hi|lo] pairs
    const float* src;
    u16* dst;
    int id;
    if (bid < 4096)      { src = x;  dst = x2;   id = bid * 256 + t; }
    else if (bid < 5120) { src = Wq; dst = Wqm2; id = (bid - 4096) * 256 + t; }
    else if (bid < 6144) { src = Wk; dst = Wk2;  id = (bid - 5120) * 256 + t; }
    else                 { src = Wv; dst = Wv2;  id = (bid - 6144) * 256 + t; }
    int flat = id * 4;
    int o = flat >> 10, i = flat & 1023;
    f4v v = *(const f4v*)(src + (size_t)flat);
    u16x4 hi, lo;
#pragma unroll
    for (int e = 0; e < 4; e++) {
      u16 h = f2bf(v[e]);
      hi[e] = h;
      lo[e] = f2bf(v[e] - bf2f(h));
    }
    size_t base = (size_t)o * 2048 + i;
    *(u16x4*)(dst + base) = hi;
    *(u16x4*)(dst + base + 1024) = lo;
  } else if (bid < 9216) {                // transposes (C->Ct2, Wq->WqT2)
    const float* src = (bid < 8192) ? C : Wq;
    u16* dst = (bid < 8192) ? Ct2 : WqT2;
    int tt = (bid < 8192) ? (bid - 7168) : (bid - 8192);
    int lx = t & 31, ly = t >> 5;
    int i0 = (tt & 31) * 32, j0 = (tt >> 5) * 32;
#pragma unroll
    for (int r = 0; r < 32; r += 8)
      tb[ly + r][lx] = src[(size_t)(i0 + ly + r) * 1024 + j0 + lx];
    __syncthreads();
#pragma unroll
    for (int r = 0; r < 32; r += 8) {
      float f = tb[lx][ly + r];           // = src[i0+lx][j0+ly+r]
      u16 h = f2bf(f);
      u16 l = f2bf(f - bf2f(h));
      size_t o = (size_t)(j0 + ly + r) * 2048 + i0 + lx;
      dst[o] = h;
      dst[o + 1024] = l;
    }
  } else if (bid < 9228) {                // biases
    int id = (bid - 9216) * 256 + t;
    float v = (id < 1024) ? bq[id] : (id < 2048) ? bk[id - 1024] : bv[id - 2048];
    bp[id] = v;
  } else if (bid == 9228) {               // bm scan -> idx, cnt
    int c = 0;
    for (int e = 0; e < 16; e++) {
      int r = t * 16 + e;
      if (bm[r] != 0.0f) c++;
    }
    ps[t] = c;
    __syncthreads();
    for (int off = 1; off < 256; off <<= 1) {
      int v = (t >= off) ? ps[t - off] : 0;
      __syncthreads();
      ps[t] += v;
      __syncthreads();
    }
    int p = ps[t] - c;
    for (int e = 0; e < 16; e++) {
      int r = t * 16 + e;
      if (bm[r] != 0.0f) idx[p++] = r;
    }
    int cn = ps[255];
    if (t == 0) cntp[0] = cn;
    for (int r = cn + t; r < 4096; r += 256) idx[r] = 0;
  } else {                                // b1 = bq @ C  (4 blocks x 256)
    int j = (bid - 9229) * 256 + t;
    float a = 0.f;
    for (int d = 0; d < 1024; d++) a += bq[d] * C[(size_t)d * 1024 + j];
    b1[j] = a;
  }
}

// ---------------- NT GEMM core, 128x128, BK=64 + XOR bank swizzle ----------
// C[M,N] = A[M,K] @ B[N,K]^T, bf16 in, fp32 accum, 128x128 tile, 4 waves,
// 16x16x32 bf16 MFMA, global_load_lds width 16, 64-deep K-step.
// triple=1: virtual K=3072 over 2-term [hi|lo] storage (width 2048):
//   A-side [hi|lo|hi]: k0a = k0>=2048 ? k0-2048 : k0
//   B-side [hi|hi|lo]: k0b = k0>=1024 ? k0-1024 : k0
// (64-step never straddles a 1024 boundary; values identical to the old
// 6B/elem triple buffers -> bitwise-same MFMA sequence as R14.)
// Optional ridx: A-side row gather. LDS swizzle: row r chunk c at slot
// c ^ (r&7); 0 bank conflicts (verified R7). ONE call site per kernel (R9
// lesson: each inlined call site gets its own 32KB LDS allocation).

struct EpiG1 {  // mode 0: k2 [hi|lo]; 1: q(plain hi)|qc2 [hi|lo]; 2: vt
  const float* bp; const float* b1;
  u16* qs; u16* k2; u16* qc2; u16* vt; int mode;
  __device__ void operator()(int r, int c, float v) const {
    if (mode == 0) {
      v += bp[1024 + c];
      u16 h = f2bf(v);
      size_t b = (size_t)r * 2048 + c;
      k2[b] = h;
      k2[b + 1024] = f2bf(v - bf2f(h));
    } else if (mode == 1) {
      if (c < 1024) {
        qs[(size_t)r * 1024 + c] = f2bf(v + bp[c]);
      } else {
        float w = v + b1[c - 1024];
        u16 h = f2bf(w);
        size_t b = (size_t)r * 2048 + (c - 1024);
        qc2[b] = h;
        qc2[b + 1024] = f2bf(w - bf2f(h));
      }
    } else {
      v += bp[2048 + r];
      vt[(size_t)r * 4096 + c] = f2bf(v);
    }
  }
};

struct EpiM1 {        // M1T split-K partial store (r = M1T row j, c = col i)
  float* part;
  __device__ void operator()(int r, int c, float v) const {
    part[(size_t)r * 1024 + c] = v;
  }
};

struct EpiSCL {       // merged S | CL epilogue (compact rows)
  u16* Sc; u8* st; float b0; int isS;
  __device__ void operator()(int r, int c, float v) const {
    if (isS) Sc[(size_t)r * 4096 + c] = f2bf(v);
    else st[(size_t)r * 4096 + c] = (v + b0 > 0.f) ? 1 : 0;
  }
};

struct EpiPart {      // PV split-K: scatter partial to original row space
  float* part; const int* idx; int cnt;
  __device__ void operator()(int r, int c, float v) const {
    if (r < cnt) part[(size_t)idx[r] * 1024 + c] = v;
  }
};

template <class Epi>
__device__ __forceinline__ void gemm_core(
    const u16* __restrict__ A, const u16* __restrict__ B,
    int lda, int ldb, int kStart, int kEnd, int triple,
    int mBase, int nBase, const int* __restrict__ ridx, Epi epi) {
  __shared__ __align__(16) u16 lA[128 * 64];
  __shared__ __align__(16) u16 lB[128 * 64];
  const int tid = threadIdx.x;
  const int wave = tid >> 6, lane = tid & 63;
  const int wm = wave & 1, wn = wave >> 1;
  const int lane16 = lane & 15, quad = lane >> 4;

  const int srow = tid >> 3;
  const int gchunk = ((tid & 7) ^ (srow & 7)) * 8;
  const u16* aPi[4];
#pragma unroll
  for (int i = 0; i < 4; i++) {
    int row = mBase + srow + 32 * i;
    int g = ridx ? ridx[row] : row;
    aPi[i] = A + (size_t)g * lda + gchunk;
  }
  const u16* bP = B + (size_t)(nBase + srow) * ldb + gchunk;
  const int woff = wave * 1024;

  const int rsw = lane16 & 7;
  const u16* raB = lA + (wm * 64 + lane16) * 64;
  const u16* rbB = lB + (wn * 64 + lane16) * 64;

  f32x4 acc[4][4];
#pragma unroll
  for (int i = 0; i < 4; i++)
#pragma unroll
    for (int j = 0; j < 4; j++) acc[i][j] = (f32x4){0.f, 0.f, 0.f, 0.f};

  for (int k0 = kStart; k0 < kEnd; k0 += 64) {
    int k0a = k0, k0b = k0;
    if (triple) {
      k0a = (k0 >= 2048) ? (k0 - 2048) : k0;
      k0b = (k0 >= 1024) ? (k0 - 1024) : k0;
    }
#pragma unroll
    for (int i = 0; i < 4; i++) {
      gld16((char*)lA + i * 4096 + woff, aPi[i] + k0a);
      gld16((char*)lB + i * 4096 + woff, bP + (size_t)(32 * i) * ldb + k0b);
    }
    __syncthreads();
    short8 af[2][4], bfr[2][4];
#pragma unroll
    for (int s = 0; s < 2; s++) {
      const int sl = (((s << 2) + quad) ^ rsw) * 8;
#pragma unroll
      for (int j = 0; j < 4; j++) {
        af[s][j]  = *(const short8*)(raB + j * 1024 + sl);
        bfr[s][j] = *(const short8*)(rbB + j * 1024 + sl);
      }
    }
#pragma unroll
    for (int s = 0; s < 2; s++)
#pragma unroll
      for (int im = 0; im < 4; im++)
#pragma unroll
        for (int in = 0; in < 4; in++)
          acc[im][in] = __builtin_amdgcn_mfma_f32_16x16x32_bf16(
              af[s][im], bfr[s][in], acc[im][in], 0, 0, 0);
    __syncthreads();
  }

#pragma unroll
  for (int im = 0; im < 4; im++)
#pragma unroll
    for (int in = 0; in < 4; in++)
#pragma unroll
      for (int i = 0; i < 4; i++) {
        int r = mBase + wm * 64 + im * 16 + quad * 4 + i;
        int c = nBase + wn * 64 + in * 16 + lane16;
        epi(r, c, acc[im][in][i]);
      }
}

// M1T = C^T @ Wq (virtual K=3072 triple), split-K=4 (768 each). 256 blocks.
//   out[j][i] = sum_d Ct[j][d]*WqT[i][d] = M1[i][j].
__global__ __launch_bounds__(256, 3) void gemm_m1(
    const u16* __restrict__ Ct2, const u16* __restrict__ WqT2,
    float* __restrict__ parts) {
  const int z = blockIdx.x >> 6, tile = blockIdx.x & 63;
  gemm_core(Ct2, WqT2, 2048, 2048, z * 768, z * 768 + 768, 1,
            (tile >> 3) * 128, (tile & 7) * 128, nullptr,
            EpiM1{parts + (size_t)z * 1024 * 1024});
}

// combine M1T partials -> [hi|lo] into Wqm2 rows 1024..2047.
__global__ void m1fin(const float* __restrict__ parts, u16* __restrict__ Wqm2) {
  int flat = (blockIdx.x * 256 + threadIdx.x) * 4;
  int j = flat >> 10, i = flat & 1023;
  const size_t SL = (size_t)1024 * 1024;
  f4v p0 = *(const f4v*)(parts + (size_t)flat);
  f4v p1 = *(const f4v*)(parts + SL + flat);
  f4v p2 = *(const f4v*)(parts + 2 * SL + flat);
  f4v p3 = *(const f4v*)(parts + 3 * SL + flat);
  u16x4 hi, lo;
#pragma unroll
  for (int e = 0; e < 4; e++) {
    float f = (p0[e] + p1[e]) + (p2[e] + p3[e]);
    u16 h = f2bf(f);
    hi[e] = h;
    lo[e] = f2bf(f - bf2f(h));
  }
  size_t base = (size_t)(1024 + j) * 2048 + i;
  *(u16x4*)(Wqm2 + base) = hi;
  *(u16x4*)(Wqm2 + base + 1024) = lo;
}

// G1 job-loop kernel, grid 768 = 3/CU, ONE gemm_core call site (R14 map):
//  bid<256:        k-tile (triple K=3072): m=(bid>>3)*128, n=(bid&7)*128
//  bid in [256,544): q|qc tile (triple, N=2048): t=bid-256, m=(t>>4)*128
//                  (m-tiles 0..17; exit if >=cnt)
//  bid>=544 (224 blocks):
//    pass0: q|qc overflow tile 18+(t>>4) (normally dead, any-cnt correct),
//    pass1/2: vt tiles t and t+224 (K=1024 plain).
__global__ __launch_bounds__(256, 3) void gemm_g1(
    const u16* __restrict__ x2, const u16* __restrict__ Wk2,
    const u16* __restrict__ Wv2, const u16* __restrict__ Wqm2,
    const float* __restrict__ bp, const float* __restrict__ b1,
    u16* __restrict__ qs, u16* __restrict__ k2, u16* __restrict__ qc2,
    u16* __restrict__ vt, const int* __restrict__ idx,
    const int* __restrict__ cntp) {
  const int bid = blockIdx.x;
  const int cnt = cntp[0];
  for (int pass = 0; pass < 3; ++pass) {
    const u16 *A, *B;
    const int* rx = nullptr;
    int kEnd, trip, mB, nB, mode;
    if (bid < 256) {
      if (pass) break;
      A = x2; B = Wk2; kEnd = 3072; trip = 1;
      mB = (bid >> 3) * 128; nB = (bid & 7) * 128; mode = 0;
    } else if (bid < 544) {
      if (pass) break;
      const int t = bid - 256;
      mB = (t >> 4) * 128;
      if (mB >= cnt) break;
      A = x2; B = Wqm2; kEnd = 3072; trip = 1;
      nB = (t & 15) * 128; rx = idx; mode = 1;
    } else {
      const int t = bid - 544;
      if (pass == 0) {                     // overflow q|qc (m-tiles 18..31)
        mB = (18 + (t >> 4)) * 128;
        if (mB >= cnt) continue;           // normally dead -> fall to vt
        A = x2; B = Wqm2; kEnd = 3072; trip = 1;
        nB = (t & 15) * 128; rx = idx; mode = 1;
      } else {                             // vt jobs t and t+224
        const int s = t + (pass - 1) * 224;
        if (s >= 256) break;
        A = Wv2; B = x2; kEnd = 1024; trip = 0;
        mB = (s & 7) * 128; nB = (s >> 3) * 128; mode = 2;
      }
    }
    gemm_core(A, B, 2048, 2048, 0, kEnd, trip, mB, nB, rx,
              EpiG1{bp, b1, qs, k2, qc2, vt, mode});
  }
}

// merged S | CL kernel, grid 2048, live-first m-major, ONE call site:
//  bid<1024:  CL = qc2@k2^T triple K=3072: m=(bid>>5)*128 (exit), n=(bid&31)*128
//  bid>=1024: S  = qs@k2_hi^T plain K=1024: t=bid-1024, same tiling
__global__ __launch_bounds__(256, 3) void gemm_scl(
    const u16* __restrict__ qs, const u16* __restrict__ qc2,
    const u16* __restrict__ k2, const float* __restrict__ bias,
    u16* __restrict__ Sc, u8* __restrict__ st,
    const int* __restrict__ cntp) {
  const int bid = blockIdx.x;
  const int cnt = cntp[0];
  const u16* A;
  int lda, kEnd, trip, mB, nB, isS;
  if (bid < 1024) {
    mB = (bid >> 5) * 128;
    if (mB >= cnt) return;
    A = qc2; lda = 2048; kEnd = 3072; trip = 1; nB = (bid & 31) * 128; isS = 0;
  } else {
    const int t = bid - 1024;
    mB = (t >> 5) * 128;
    if (mB >= cnt) return;
    A = qs; lda = 1024; kEnd = 1024; trip = 0; nB = (t & 31) * 128; isS = 1;
  }
  gemm_core(A, k2, lda, 2048, 0, kEnd, trip, mB, nB, nullptr,
            EpiSCL{Sc, st, bias[0], isS});
}

// PV split-K=4, grid 1024, m-major: m=bid>>5 (exit if m*128>=cnt),
// rem=bid&31: z=rem>>3, n=rem&7.
__global__ __launch_bounds__(256, 3) void gemm_pv(
    const u16* __restrict__ P, const u16* __restrict__ vt,
    float* __restrict__ p01, float* __restrict__ p23,
    const int* __restrict__ idx, const int* __restrict__ cntp) {
  const int bid = blockIdx.x;
  const int m = bid >> 5, rem = bid & 31;
  const int z = rem >> 3, n = rem & 7;
  const int cnt = cntp[0];
  const int mBase = m * 128;
  if (mBase >= cnt) return;
  float* base = ((z < 2) ? p01 : p23) + (size_t)(z & 1) * (4096ull * 1024ull);
  const size_t kOff = (size_t)z * 1024;
  gemm_core(P + kOff, vt + kOff, 4096, 4096, 0, 1024, 0, mBase, n * 128,
            nullptr, EpiPart{base, idx, cnt});
}

// out = (1-bm)*x + bm*(p0+p1+p2+p3); bm==0 rows skip partial loads.
__global__ void reduce_out(const float* __restrict__ x, const float* __restrict__ bm,
                           const float* __restrict__ p01, const float* __restrict__ p23,
                           float* __restrict__ out) {
  int id = blockIdx.x * 256 + threadIdx.x;
  int flat = id * 4;
  int r = flat >> 10;
  float b = bm[r];
  f4v xv = *(const f4v*)(x + (size_t)flat);
  f4v o;
  if (b != 0.0f) {
    const size_t SL = (size_t)4096 * 1024;
    f4v a0 = *(const f4v*)(p01 + (size_t)flat);
    f4v a1 = *(const f4v*)(p01 + SL + flat);
    f4v a2 = *(const f4v*)(p23 + (size_t)flat);
    f4v a3 = *(const f4v*)(p23 + SL + flat);
#pragma unroll
    for (int e = 0; e < 4; e++)
      o[e] = b * ((a0[e] + a1[e]) + (a2[e] + a3[e])) + (1.0f - b) * xv[e];
  } else {
    o = xv;
  }
  *(f4v*)(out + (size_t)flat) = o;
}

// ---------------- mask + softmax (compact rows, am/lm gathered) ------------
__global__ __launch_bounds__(256) void mask_softmax(
    const u16* __restrict__ Sc, const u8* __restrict__ st,
    const float* __restrict__ am, const float* __restrict__ lm,
    u16* __restrict__ P, const int* __restrict__ idx,
    const int* __restrict__ cntp) {
  const int n = blockIdx.x, tid = threadIdx.x;
  if (n >= cntp[0]) return;
  const int orow = idx[n];
  const int lane = tid & 63, wave = tid >> 6;
  const u16* Srow = Sc + (size_t)n * 4096;
  const u8* Trow = st + (size_t)n * 4096;
  const float* Arow = am + (size_t)orow * 4096;
  const float* Lrow = lm + (size_t)orow * 4096;

  float lg[16];
  float mx = -3.4e38f;
#pragma unroll
  for (int j = 0; j < 2; j++) {
    int base = (tid + 256 * j) * 8;
    u16x8 s8 = *(const u16x8*)(Srow + base);
    unsigned long long t8 = *(const unsigned long long*)(Trow + base);
    f4v a0 = *(const f4v*)(Arow + base), a1 = *(const f4v*)(Arow + base + 4);
    f4v l0 = *(const f4v*)(Lrow + base), l1 = *(const f4v*)(Lrow + base + 4);
#pragma unroll
    for (int e = 0; e < 8; e++) {
      float stv = ((t8 >> (8 * e)) & 1ull) ? 1.f : 0.f;
      float a = (e < 4) ? a0[e] : a1[e - 4];
      float l = (e < 4) ? l0[e] : l1[e - 4];
      float mv = a + stv * l;
      float v = bf2f(s8[e]) * 0.03125f - 10000.f * (1.f - mv);
      lg[j * 8 + e] = v;
      mx = fmaxf(mx, v);
    }
  }
#pragma unroll
  for (int o = 32; o; o >>= 1) mx = fmaxf(mx, __shfl_xor(mx, o));
  __shared__ float smax[4], ssum[4];
  if (lane == 0) smax[wave] = mx;
  __syncthreads();
  mx = fmaxf(fmaxf(smax[0], smax[1]), fmaxf(smax[2], smax[3]));

  float sum = 0.f;
#pragma unroll
  for (int i = 0; i < 16; i++) { lg[i] = __expf(lg[i] - mx); sum += lg[i]; }
#pragma unroll
  for (int o = 32; o; o >>= 1) sum += __shfl_xor(sum, o);
  if (lane == 0) ssum[wave] = sum;
  __syncthreads();
  float inv = 1.f / (ssum[0] + ssum[1] + ssum[2] + ssum[3]);

  u16* Pr = P + (size_t)n * 4096;
#pragma unroll
  for (int j = 0; j < 2; j++) {
    int base = (tid + 256 * j) * 8;
    u16x8 o8;
#pragma unroll
    for (int e = 0; e < 8; e++) o8[e] = f2bf(lg[j * 8 + e] * inv);
    *(u16x8*)(Pr + base) = o8;
  }
}

// ---------------- launch ----------------

extern "C" void kernel_launch(void* const* d_in, const int* in_sizes, int n_in,
                              void* d_out, int out_size, void* d_ws, size_t ws_size,
                              hipStream_t stream) {
  const float* x    = (const float*)d_in[0];
  const float* am   = (const float*)d_in[1];
  const float* lm   = (const float*)d_in[2];
  const float* bm   = (const float*)d_in[3];
  const float* Wq   = (const float*)d_in[4];
  const float* bq   = (const float*)d_in[5];
  const float* Wk   = (const float*)d_in[6];
  const float* bk   = (const float*)d_in[7];
  const float* Wv   = (const float*)d_in[8];
  const float* bv   = (const float*)d_in[9];
  const float* Cc   = (const float*)d_in[10];
  const float* bias = (const float*)d_in[11];
  float* out = (float*)d_out;
  char* ws = (char*)d_ws;

  if (ws_size < 0xB010000) return;  // ~176 MB scratch

  u16*  x2   = (u16*) (ws + 0x0000000);  // 16 MB [x_hi|x_lo] w2048
  u16*  Wqm2 = (u16*) (ws + 0x1000000);  //  8 MB [Wq ; M1T] w2048
  u16*  Wk2  = (u16*) (ws + 0x1800000);  //  4 MB
  u16*  Wv2  = (u16*) (ws + 0x1C00000);  //  4 MB
  u16*  Ct2  = (u16*) (ws + 0x2000000);  //  4 MB C^T
  u16*  WqT2 = (u16*) (ws + 0x2400000);  //  4 MB Wq^T
  float* bp  = (float*)(ws + 0x2800000); // 12 KB
  float* b1  = (float*)(ws + 0x2804000); //  4 KB bq@C
  int*  idx  = (int*)  (ws + 0x2808000); // 16 KB compact->orig row map
  int*  cnt  = (int*)  (ws + 0x280C000); //  4 B
  u16*  qs   = (u16*) (ws + 0x2900000);  //  8 MB q hi (plain, compact)
  u16*  qc2  = (u16*) (ws + 0x3100000);  // 16 MB [qc_hi|qc_lo] (compact)
  u16*  k2   = (u16*) (ws + 0x4100000);  // 16 MB [k_hi|k_lo] (full)
  u16*  vt   = (u16*) (ws + 0x5100000);  //  8 MB v^T [1024,4096]
  u16*  Sc   = (u16*) (ws + 0x5900000);  // 32 MB bf16 S (compact)
  u8*   st   = (u8*)  (ws + 0x7900000);  // 16 MB st bits (compact)
  u16*  P    = (u16*) (ws + 0x8900000);  // 32 MB softmax out; end 0xA900000
  // overlays:
  float* m1parts = (float*)(ws + 0x5900000); // 16 MB (Sc region; dead pre-SCL)
  float* parts01 = (float*)(ws + 0x5900000); // 32 MB (Sc, dead post-softmax)
  float* parts23 = (float*)(ws + 0x0000000); // 32 MB (x2..Wv2, dead post-G1)

  // preps: [hi|lo] casts, C^T, Wq^T, biases, bm-scan, b1
  prep_all<<<9233, 256, 0, stream>>>(x, Wq, Wk, Wv, bq, bk, bv, Cc, bm,
                                     x2, Wqm2, Wk2, Wv2, Ct2, WqT2,
                                     bp, b1, idx, cnt);
  // M1T = C^T @ Wq (triple, split-K=4) -> partials -> Wqm2 rows 1024..2047
  gemm_m1<<<256, 256, 0, stream>>>(Ct2, WqT2, m1parts);
  m1fin<<<1024, 256, 0, stream>>>(m1parts, Wqm2);
  // G1 job-loop: k | q,qc (fused vs [Wq;M1T], gathered rows) | vt
  gemm_g1<<<768, 256, 0, stream>>>(x2, Wk2, Wv2, Wqm2, bp, b1,
                                   qs, k2, qc2, vt, idx, cnt);
  // merged S | CL (CL blocks first; S backfills)
  gemm_scl<<<2048, 256, 0, stream>>>(qs, qc2, k2, bias, Sc, st, cnt);
  // mask + softmax -> P (bf16, compact rows)
  mask_softmax<<<4096, 256, 0, stream>>>(Sc, st, am, lm, P, idx, cnt);
  // PV: parts[z] = P @ vt^T over K-quarters, scattered to original rows
  gemm_pv<<<1024, 256, 0, stream>>>(P, vt, parts01, parts23, idx, cnt);
  // out = (1-bm)x + bm*(p0+p1+p2+p3)
  reduce_out<<<4096, 256, 0, stream>>>(x, bm, parts01, parts23, out);
}